// Round 2
// baseline (8925.233 us; speedup 1.0000x reference)
//
#include <hip/hip_runtime.h>
#include <hip/hip_bf16.h>

#define FEATS 64
#define XDIM 67
#define EIN_D 133
#define H1 266
#define KPAD 136      // k padded to multiple of 4
#define JPAD 272      // j padded (zero cols 266..271)
#define EDGES_PER_BLOCK 64

__device__ __forceinline__ float silu_f(float x) {
    return x / (1.f + __expf(-x));
}

// ---------------- utility: zero-fill / copy (graph-capture-safe) ----------------
__global__ void zero_kernel(float* __restrict__ p, int n) {
    int n4 = n >> 2;
    float4* p4 = (float4*)p;
    for (int i = blockIdx.x * blockDim.x + threadIdx.x; i < n4; i += gridDim.x * blockDim.x)
        p4[i] = make_float4(0.f, 0.f, 0.f, 0.f);
    if (blockIdx.x == 0 && threadIdx.x == 0)
        for (int i = n4 * 4; i < n; ++i) p[i] = 0.f;
}

__global__ void copy_kernel(const float* __restrict__ src, float* __restrict__ dst, int n) {
    int n4 = n >> 2;
    const float4* s4 = (const float4*)src;
    float4* d4 = (float4*)dst;
    for (int i = blockIdx.x * blockDim.x + threadIdx.x; i < n4; i += gridDim.x * blockDim.x)
        d4[i] = s4[i];
    if (blockIdx.x == 0 && threadIdx.x == 0)
        for (int i = n4 * 4; i < n; ++i) dst[i] = src[i];
}

// ---------------- prep: pad w1 / b1 into zero-padded layouts ----------------
__global__ void prep_w1(const float* __restrict__ w1, float* __restrict__ w1p) {
    int idx = blockIdx.x * 256 + threadIdx.x;
    const int per_layer = KPAD * JPAD;
    if (idx >= 3 * per_layer) return;
    int l = idx / per_layer;
    int rem = idx - l * per_layer;
    int k = rem / JPAD, j = rem - (rem / JPAD) * JPAD;
    w1p[idx] = (k < EIN_D && j < H1) ? w1[(l * EIN_D + k) * H1 + j] : 0.f;
}

__global__ void prep_b1(const float* __restrict__ b1, float* __restrict__ b1p) {
    int idx = blockIdx.x * 256 + threadIdx.x;
    if (idx >= 3 * JPAD) return;
    int l = idx / JPAD, j = idx - l * JPAD;
    b1p[idx] = (j < H1) ? b1[l * H1 + j] : 0.f;
}

// ---------------- fused edge kernel ----------------
// block: 256 threads, 64 edges. thread (te=tid>>4, tj=tid&15):
// edges e0..e0+3 (e0=te*4), cols tj*4 (+64*g)

template<int NG>
__device__ __forceinline__ void mlp1_chunk(int j0, int tj, int e0,
    const float (*ein)[140], const float* __restrict__ w1p, const float* __restrict__ b1p,
    const float (*ew2t)[JPAD], float macc[4][16])
{
    int jb[NG];
#pragma unroll
    for (int g = 0; g < NG; ++g) {
        int j = j0 + g * 64 + tj * 4;
        jb[g] = (j > 268) ? 268 : j;   // clamp into zero-pad region
    }
    float hacc[4][NG * 4];
#pragma unroll
    for (int i = 0; i < 4; ++i)
#pragma unroll
        for (int u = 0; u < NG * 4; ++u) hacc[i][u] = 0.f;

#pragma unroll 2
    for (int kk = 0; kk < KPAD; kk += 4) {
        float4 a[4];
#pragma unroll
        for (int i = 0; i < 4; ++i)
            a[i] = *(const float4*)&ein[e0 + i][kk];
#pragma unroll
        for (int dk = 0; dk < 4; ++dk) {
#pragma unroll
            for (int g = 0; g < NG; ++g) {
                float4 w = *(const float4*)&w1p[(kk + dk) * JPAD + jb[g]];
#pragma unroll
                for (int i = 0; i < 4; ++i) {
                    float av = (dk == 0) ? a[i].x : (dk == 1) ? a[i].y : (dk == 2) ? a[i].z : a[i].w;
                    hacc[i][g * 4 + 0] += av * w.x;
                    hacc[i][g * 4 + 1] += av * w.y;
                    hacc[i][g * 4 + 2] += av * w.z;
                    hacc[i][g * 4 + 3] += av * w.w;
                }
            }
        }
    }
    // bias + silu  (padded cols: bias=0, acc=0 -> silu(0)=0)
#pragma unroll
    for (int g = 0; g < NG; ++g) {
        float4 bv = *(const float4*)&b1p[jb[g]];
#pragma unroll
        for (int i = 0; i < 4; ++i) {
            hacc[i][g * 4 + 0] = silu_f(hacc[i][g * 4 + 0] + bv.x);
            hacc[i][g * 4 + 1] = silu_f(hacc[i][g * 4 + 1] + bv.y);
            hacc[i][g * 4 + 2] = silu_f(hacc[i][g * 4 + 2] + bv.z);
            hacc[i][g * 4 + 3] = silu_f(hacc[i][g * 4 + 3] + bv.w);
        }
    }
    // MLP2 partial accumulation (padded cols have zero ew2t -> contribute 0)
#pragma unroll
    for (int c = 0; c < 16; ++c) {
#pragma unroll
        for (int g = 0; g < NG; ++g) {
            float4 wv = *(const float4*)&ew2t[c][jb[g]];
#pragma unroll
            for (int i = 0; i < 4; ++i) {
                macc[i][c] += hacc[i][g * 4 + 0] * wv.x + hacc[i][g * 4 + 1] * wv.y
                            + hacc[i][g * 4 + 2] * wv.z + hacc[i][g * 4 + 3] * wv.w;
            }
        }
    }
}

__global__ __launch_bounds__(256) void edge_kernel(
    const float* __restrict__ x,          // N x 67 (current layer's x)
    const int* __restrict__ eidx,         // 2 x E  (int32! harness casts int64->int32)
    const float* __restrict__ eattr,      // E x 4
    const float* __restrict__ w1p,        // [136][272] padded
    const float* __restrict__ b1p,        // [272] padded
    const float* __restrict__ w2,         // 266 x 16
    const float* __restrict__ b2,         // 16
    const float* __restrict__ cw1,        // 16 x 64
    const float* __restrict__ cb1,        // 64
    const float* __restrict__ cw2,        // 64
    const float* __restrict__ cb2,        // 1
    float* __restrict__ m_i,              // N x 16
    float* __restrict__ cri,              // N x 3
    float* __restrict__ cwi,              // N
    int E, int N)
{
    __shared__ __align__(16) float ein[EDGES_PER_BLOCK][140];   // cols 0..132 data, 133..139 zero
    __shared__ __align__(16) float ew2t[16][JPAD];              // transposed ew2, zero-padded
    __shared__ float mij[EDGES_PER_BLOCK][17];
    __shared__ float relc[EDGES_PER_BLOCK][4];                  // xyz + coor_w
    __shared__ int   dstl[EDGES_PER_BLOCK];

    const int tid = threadIdx.x;
    const int ge0 = blockIdx.x * EDGES_PER_BLOCK;

    // ---- stage ew2 transposed into LDS (zero-padded) ----
    for (int idx = tid; idx < 16 * JPAD; idx += 256) {
        int c = idx / JPAD, j = idx - c * JPAD;
        ew2t[c][j] = (j < H1) ? w2[j * 16 + c] : 0.f;
    }

    // ---- gather edge_in ----
    {
        const int wv = tid >> 6, lane = tid & 63;
        for (int q = 0; q < 16; ++q) {
            int e = wv * 16 + q;
            int ge = ge0 + e;
            if (ge < E) {
                int s = eidx[ge];
                int d = eidx[E + ge];
                const float* xs = x + (long long)s * XDIM;
                const float* xd = x + (long long)d * XDIM;
                ein[e][lane]      = xd[lane];   // feats[dst]
                ein[e][64 + lane] = xs[lane];   // feats[src]
                if (lane < 4) ein[e][128 + lane] = eattr[(long long)ge * 4 + lane];
                if (lane < 7) ein[e][133 + lane] = 0.f;
                if (lane == 0) {
                    float r0 = xs[64] - xd[64];
                    float r1 = xs[65] - xd[65];
                    float r2 = xs[66] - xd[66];
                    relc[e][0] = r0; relc[e][1] = r1; relc[e][2] = r2;
                    ein[e][132] = r0 * r0 + r1 * r1 + r2 * r2;
                    dstl[e] = d;
                }
            } else {
                ein[e][lane] = 0.f; ein[e][64 + lane] = 0.f;
                if (lane < 4) ein[e][128 + lane] = 0.f;
                if (lane < 7) ein[e][133 + lane] = 0.f;
                if (lane == 0) {
                    relc[e][0] = relc[e][1] = relc[e][2] = 0.f;
                    ein[e][132] = 0.f; dstl[e] = 0;
                }
            }
        }
    }
    __syncthreads();

    const int tj = tid & 15, te = tid >> 4;
    const int e0 = te * 4;

    // ---- MLP1 + MLP2 partials ----
    float macc[4][16];
#pragma unroll
    for (int i = 0; i < 4; ++i)
#pragma unroll
        for (int c = 0; c < 16; ++c) macc[i][c] = 0.f;

    mlp1_chunk<2>(0,   tj, e0, ein, w1p, b1p, ew2t, macc);
    mlp1_chunk<2>(128, tj, e0, ein, w1p, b1p, ew2t, macc);
    mlp1_chunk<1>(256, tj, e0, ein, w1p, b1p, ew2t, macc);

    // ---- reduce MLP2 partials across 16 tj lanes, bias, silu ----
#pragma unroll
    for (int i = 0; i < 4; ++i) {
#pragma unroll
        for (int c = 0; c < 16; ++c) {
            float v = macc[i][c];
            v += __shfl_xor(v, 1, 16);
            v += __shfl_xor(v, 2, 16);
            v += __shfl_xor(v, 4, 16);
            v += __shfl_xor(v, 8, 16);
            macc[i][c] = silu_f(v + b2[c]);
        }
    }
    if (tj == 0) {
#pragma unroll
        for (int i = 0; i < 4; ++i)
#pragma unroll
            for (int c = 0; c < 16; ++c) mij[e0 + i][c] = macc[i][c];
    }
    __syncthreads();

    // ---- coors MLP: silu(m @ cw1 + cb1) @ cw2 + cb2 ----
    {
        float cacc[4][4];
#pragma unroll
        for (int i = 0; i < 4; ++i)
#pragma unroll
            for (int u = 0; u < 4; ++u) cacc[i][u] = 0.f;
#pragma unroll
        for (int k = 0; k < 16; ++k) {
            float4 wvv = *(const float4*)&cw1[k * 64 + tj * 4];
#pragma unroll
            for (int i = 0; i < 4; ++i) {
                float av = mij[e0 + i][k];
                cacc[i][0] += av * wvv.x;
                cacc[i][1] += av * wvv.y;
                cacc[i][2] += av * wvv.z;
                cacc[i][3] += av * wvv.w;
            }
        }
        float4 cb1v = *(const float4*)&cb1[tj * 4];
        float4 cw2v = *(const float4*)&cw2[tj * 4];
        float cb2v = cb2[0];
#pragma unroll
        for (int i = 0; i < 4; ++i) {
            float pw = silu_f(cacc[i][0] + cb1v.x) * cw2v.x
                     + silu_f(cacc[i][1] + cb1v.y) * cw2v.y
                     + silu_f(cacc[i][2] + cb1v.z) * cw2v.z
                     + silu_f(cacc[i][3] + cb1v.w) * cw2v.w;
            pw += __shfl_xor(pw, 1, 16);
            pw += __shfl_xor(pw, 2, 16);
            pw += __shfl_xor(pw, 4, 16);
            pw += __shfl_xor(pw, 8, 16);
            if (tj == 0) relc[e0 + i][3] = pw + cb2v;
        }
    }
    __syncthreads();

    // ---- scatter: segment sums via atomics ----
    for (int idx = tid; idx < EDGES_PER_BLOCK * 16; idx += 256) {
        int e = idx >> 4, c = idx & 15;
        if (ge0 + e < E) {
            int d = dstl[e];
            atomicAdd(&m_i[(long long)d * 16 + c], mij[e][c]);
        }
    }
    for (int idx = tid; idx < EDGES_PER_BLOCK * 4; idx += 256) {
        int e = idx >> 2, c = idx & 3;
        if (ge0 + e < E) {
            int d = dstl[e];
            if (c < 3) atomicAdd(&cri[(long long)d * 3 + c], relc[e][c]);
            else       atomicAdd(&cwi[d], relc[e][3]);
        }
    }
}

// ---------------- node kernel: 2 nodes per 256-thread block ----------------
// IN-PLACE SAFE: xin may alias xout. Each row is owned by exactly one block;
// all xin reads of a given element happen in the same thread before its write,
// and feats inputs are staged to LDS before any write.
__global__ __launch_bounds__(256) void node_kernel(
    const float* xin,
    const float* __restrict__ m_i,
    const float* __restrict__ cri,
    const float* __restrict__ cwi,
    const float* __restrict__ nw1, const float* __restrict__ nb1,
    const float* __restrict__ nw2, const float* __restrict__ nb2,
    float* xout, int N)
{
    __shared__ float nin[2][80];
    __shared__ float hid[2][128];
    const int half = threadIdx.x >> 7, r = threadIdx.x & 127;
    const int n = blockIdx.x * 2 + half;
    const bool on = (n < N);

    if (on) {
        if (r < 64)      nin[half][r] = xin[(long long)n * XDIM + r];
        else if (r < 80) nin[half][r] = m_i[(long long)n * 16 + (r - 64)];
    }
    __syncthreads();
    if (on) {
        float h = nb1[r];
#pragma unroll
        for (int k = 0; k < 80; ++k) h += nin[half][k] * nw1[k * 128 + r];
        hid[half][r] = silu_f(h);
    }
    __syncthreads();
    if (on) {
        if (r < 64) {
            float o = nb2[r];
#pragma unroll
            for (int k = 0; k < 128; ++k) o += hid[half][k] * nw2[k * 64 + r];
            xout[(long long)n * XDIM + r] = o + nin[half][r];
        } else if (r < 67) {
            int c = r - 64;
            xout[(long long)n * XDIM + r] =
                xin[(long long)n * XDIM + r] + cwi[n] * cri[(long long)n * 3 + c];
        }
    }
}

extern "C" void kernel_launch(void* const* d_in, const int* in_sizes, int n_in,
                              void* d_out, int out_size, void* d_ws, size_t ws_size,
                              hipStream_t stream) {
    const float* x     = (const float*)d_in[0];
    const int*   eidx  = (const int*)d_in[1];      // int32: harness downcasts int64
    const float* eattr = (const float*)d_in[2];
    const float* ew1   = (const float*)d_in[3];
    const float* eb1   = (const float*)d_in[4];
    const float* ew2   = (const float*)d_in[5];
    const float* eb2   = (const float*)d_in[6];
    const float* cw1   = (const float*)d_in[7];
    const float* cb1   = (const float*)d_in[8];
    const float* cw2   = (const float*)d_in[9];
    const float* cb2   = (const float*)d_in[10];
    const float* nw1   = (const float*)d_in[11];
    const float* nb1   = (const float*)d_in[12];
    const float* nw2   = (const float*)d_in[13];
    const float* nb2   = (const float*)d_in[14];

    const int N = in_sizes[0] / XDIM;
    const int E = in_sizes[1] / 2;

    // ws layout (~4.25 MB): acc (N*20) | w1p (3*136*272) | b1p (3*272)
    float* acc  = (float*)d_ws;
    float* m_i  = acc;
    float* cri  = acc + (size_t)N * 16;
    float* cwi  = acc + (size_t)N * 19;
    float* w1p  = acc + (size_t)N * 20;
    float* b1p  = w1p + (size_t)3 * KPAD * JPAD;

    float* xwork = (float*)d_out;   // run all layers in place on d_out

    copy_kernel<<<2048, 256, 0, stream>>>(x, xwork, N * XDIM);
    prep_w1<<<(3 * KPAD * JPAD + 255) / 256, 256, 0, stream>>>(ew1, w1p);
    prep_b1<<<(3 * JPAD + 255) / 256, 256, 0, stream>>>(eb1, b1p);

    for (int l = 0; l < 3; ++l) {
        zero_kernel<<<1024, 256, 0, stream>>>(acc, N * 20);
        edge_kernel<<<(E + EDGES_PER_BLOCK - 1) / EDGES_PER_BLOCK, 256, 0, stream>>>(
            xwork, eidx, eattr,
            w1p + (size_t)l * KPAD * JPAD, b1p + (size_t)l * JPAD,
            ew2 + (size_t)l * H1 * 16, eb2 + (size_t)l * 16,
            cw1 + (size_t)l * 16 * 64, cb1 + (size_t)l * 64,
            cw2 + (size_t)l * 64, cb2 + l,
            m_i, cri, cwi, E, N);
        node_kernel<<<(N + 1) / 2, 256, 0, stream>>>(
            xwork, m_i, cri, cwi,
            nw1 + (size_t)l * 80 * 128, nb1 + (size_t)l * 128,
            nw2 + (size_t)l * 128 * 64, nb2 + (size_t)l * 64,
            xwork, N);
    }
}

// Round 3
// 2969.413 us; speedup vs baseline: 3.0057x; 3.0057x over previous
//
#include <hip/hip_runtime.h>
#include <hip/hip_bf16.h>

#define XDIM 67
#define EIN_D 133
#define H1 266
#define KP 160      // MLP1 K padded (133 -> 5*32)
#define KP_E 168    // ein LDS row stride (bf16; ≡40 mod 64 -> conflict-free b128)
#define JP 320      // MLP1 J padded (266 -> 20*16); also MLP2 K (10*32)
#define JP_H 328    // h / w2t LDS row stride (bf16)
#define EPB 64      // edges per block

typedef __attribute__((ext_vector_type(8))) short bf16x8;
typedef __attribute__((ext_vector_type(4))) float f32x4;

__device__ __forceinline__ float silu_f(float x) { return x / (1.f + __expf(-x)); }

__device__ __forceinline__ unsigned short bf16_rne(float f) {
    unsigned int u = __float_as_uint(f);
    u += 0x7fffu + ((u >> 16) & 1u);
    return (unsigned short)(u >> 16);
}
__device__ __forceinline__ float bf16_to_f(unsigned short h) {
    return __uint_as_float(((unsigned int)h) << 16);
}

// ---------------- utility ----------------
__global__ void zero_kernel(float* __restrict__ p, int n) {
    int n4 = n >> 2;
    float4* p4 = (float4*)p;
    for (int i = blockIdx.x * blockDim.x + threadIdx.x; i < n4; i += gridDim.x * blockDim.x)
        p4[i] = make_float4(0.f, 0.f, 0.f, 0.f);
    if (blockIdx.x == 0 && threadIdx.x == 0)
        for (int i = n4 * 4; i < n; ++i) p[i] = 0.f;
}

__global__ void copy_kernel(const float* __restrict__ src, float* __restrict__ dst, int n) {
    int n4 = n >> 2;
    const float4* s4 = (const float4*)src;
    float4* d4 = (float4*)dst;
    for (int i = blockIdx.x * blockDim.x + threadIdx.x; i < n4; i += gridDim.x * blockDim.x)
        d4[i] = s4[i];
    if (blockIdx.x == 0 && threadIdx.x == 0)
        for (int i = n4 * 4; i < n; ++i) dst[i] = src[i];
}

// ---------------- prep: split weights into bf16 hi/lo planes ----------------
// w1t: [l][JP j][KP k] (transposed, zero-padded), hi and lo planes
__global__ void prep_w1t(const float* __restrict__ ew1, unsigned short* __restrict__ whi,
                         unsigned short* __restrict__ wlo) {
    int idx = blockIdx.x * 256 + threadIdx.x;
    if (idx >= 3 * JP * KP) return;
    int l = idx / (JP * KP);
    int rem = idx - l * JP * KP;
    int j = rem / KP, k = rem - (rem / KP) * KP;
    float w = (j < H1 && k < EIN_D) ? ew1[((size_t)l * EIN_D + k) * H1 + j] : 0.f;
    unsigned short h = bf16_rne(w);
    whi[idx] = h;
    wlo[idx] = bf16_rne(w - bf16_to_f(h));
}

// w2t: [l][2 planes][16 c][JP_H j]
__global__ void prep_w2t(const float* __restrict__ ew2, unsigned short* __restrict__ w2tg) {
    int idx = blockIdx.x * 256 + threadIdx.x;
    if (idx >= 3 * 16 * JP_H) return;
    int l = idx / (16 * JP_H);
    int rem = idx - l * 16 * JP_H;
    int c = rem / JP_H, j = rem - (rem / JP_H) * JP_H;
    float w = (j < H1) ? ew2[((size_t)l * H1 + j) * 16 + c] : 0.f;
    unsigned short h = bf16_rne(w);
    w2tg[((size_t)l * 2 + 0) * 16 * JP_H + c * JP_H + j] = h;
    w2tg[((size_t)l * 2 + 1) * 16 * JP_H + c * JP_H + j] = bf16_rne(w - bf16_to_f(h));
}

__global__ void prep_b1(const float* __restrict__ b1, float* __restrict__ b1p) {
    int idx = blockIdx.x * 256 + threadIdx.x;
    if (idx >= 3 * JP) return;
    int l = idx / JP, j = idx - (idx / JP) * JP;
    b1p[idx] = (j < H1) ? b1[l * H1 + j] : 0.f;
}

// ---------------- fused edge kernel (MFMA) ----------------
// 256 thr = 4 waves, 64 edges/block.
// MLP1: C[64e][320j] = ein[64e][160k] @ w1t^T ; wave w owns j-tiles [w*5, w*5+5)
// MLP2: m[64e][16c]  = h[64e][320j] @ w2 ; wave w owns e-tile w
__global__ __launch_bounds__(256, 2) void edge_kernel(
    const float* __restrict__ x,
    const int* __restrict__ eidx,
    const float* __restrict__ eattr,
    const unsigned short* __restrict__ w1hi,   // [JP][KP] layer slice
    const unsigned short* __restrict__ w1lo,
    const float* __restrict__ b1p,             // [JP]
    const unsigned short* __restrict__ w2tg,   // [2][16][JP_H] layer slice
    const float* __restrict__ b2,              // [16]
    const float* __restrict__ cw1, const float* __restrict__ cb1,
    const float* __restrict__ cw2, const float* __restrict__ cb2,
    float* __restrict__ m_i, float* __restrict__ cri, float* __restrict__ cwi,
    int E, int N)
{
    // ein hi|lo planes; after MLP1, the same space is reused for h (bf16 hi)
    __shared__ __align__(16) unsigned short uA[2 * EPB * KP_E];   // 43008 B
    __shared__ __align__(16) unsigned short w2t[2 * 16 * JP_H];   // 20992 B
    __shared__ float mij[EPB][17];
    __shared__ float relc[EPB][4];
    __shared__ int dstl[EPB];

    unsigned short* ein_hi = uA;
    unsigned short* ein_lo = uA + EPB * KP_E;
    unsigned short* h_hi   = uA;      // EPB*JP_H = 20992 <= 21504 ok

    const int tid = threadIdx.x;
    const int lane = tid & 63;
    const int w = tid >> 6;
    const int ge0 = blockIdx.x * EPB;

    // ---- stage w2t (both planes) ----
    {
        const ulonglong2* src = (const ulonglong2*)w2tg;
        ulonglong2* dst = (ulonglong2*)w2t;
        for (int i = tid; i < 2 * 16 * JP_H / 8; i += 256) dst[i] = src[i];
    }

    // ---- gather edge_in (split to bf16 hi/lo) ----
    for (int q = 0; q < 16; ++q) {
        const int e = w * 16 + q;
        const int ge = ge0 + e;
        unsigned short* rh = ein_hi + e * KP_E;
        unsigned short* rl = ein_lo + e * KP_E;
        if (ge < E) {
            int s = eidx[ge];
            int d = eidx[E + ge];
            const float* xs = x + (size_t)s * XDIM;
            const float* xd = x + (size_t)d * XDIM;
            float vd = xd[lane], vs = xs[lane];
            unsigned short h0 = bf16_rne(vd);
            rh[lane] = h0;
            rl[lane] = bf16_rne(vd - bf16_to_f(h0));
            unsigned short h1 = bf16_rne(vs);
            rh[64 + lane] = h1;
            rl[64 + lane] = bf16_rne(vs - bf16_to_f(h1));
            if (lane < 32) { rh[128 + lane] = 0; rl[128 + lane] = 0; }
            if (lane < 4) {
                float a = eattr[(size_t)ge * 4 + lane];
                unsigned short ha = bf16_rne(a);
                rh[128 + lane] = ha;
                rl[128 + lane] = bf16_rne(a - bf16_to_f(ha));
            }
            if (lane < 5) {
                float r0 = xs[64] - xd[64], r1 = xs[65] - xd[65], r2 = xs[66] - xd[66];
                if (lane == 4) {
                    float dist = r0 * r0 + r1 * r1 + r2 * r2;
                    unsigned short hd = bf16_rne(dist);
                    rh[132] = hd;
                    rl[132] = bf16_rne(dist - bf16_to_f(hd));
                } else if (lane == 0) {
                    relc[e][0] = r0; relc[e][1] = r1; relc[e][2] = r2;
                    dstl[e] = d;
                }
            }
        } else {
            rh[lane] = 0; rl[lane] = 0;
            rh[64 + lane] = 0; rl[64 + lane] = 0;
            if (lane < 32) { rh[128 + lane] = 0; rl[128 + lane] = 0; }
            if (lane == 0) dstl[e] = 0;
        }
    }
    __syncthreads();

    const int r16 = lane & 15, g4 = lane >> 4;
    const int jt0 = w * 5;

    // ---- MLP1: bf16x3 MFMA ----
    f32x4 acc[5][4];
#pragma unroll
    for (int a = 0; a < 5; ++a)
#pragma unroll
        for (int b = 0; b < 4; ++b) acc[a][b] = (f32x4){0.f, 0.f, 0.f, 0.f};

#pragma unroll
    for (int kk = 0; kk < 5; ++kk) {
        const int ko = kk * 32 + g4 * 8;
        bf16x8 ah[4], al[4];
#pragma unroll
        for (int et = 0; et < 4; ++et) {
            ah[et] = *(const bf16x8*)&ein_hi[(et * 16 + r16) * KP_E + ko];
            al[et] = *(const bf16x8*)&ein_lo[(et * 16 + r16) * KP_E + ko];
        }
#pragma unroll
        for (int j5 = 0; j5 < 5; ++j5) {
            const size_t wo = (size_t)((jt0 + j5) * 16 + r16) * KP + ko;
            bf16x8 bh = *(const bf16x8*)&w1hi[wo];
            bf16x8 bl = *(const bf16x8*)&w1lo[wo];
#pragma unroll
            for (int et = 0; et < 4; ++et) {
                acc[j5][et] = __builtin_amdgcn_mfma_f32_16x16x32_bf16(ah[et], bh, acc[j5][et], 0, 0, 0);
                acc[j5][et] = __builtin_amdgcn_mfma_f32_16x16x32_bf16(al[et], bh, acc[j5][et], 0, 0, 0);
                acc[j5][et] = __builtin_amdgcn_mfma_f32_16x16x32_bf16(ah[et], bl, acc[j5][et], 0, 0, 0);
            }
        }
    }

    // ---- bias + silu -> h (bf16 hi), into the union buffer ----
    float b1v[5];
#pragma unroll
    for (int j5 = 0; j5 < 5; ++j5) b1v[j5] = b1p[(jt0 + j5) * 16 + r16];

    __syncthreads();   // all ein reads done before overwriting with h

#pragma unroll
    for (int j5 = 0; j5 < 5; ++j5)
#pragma unroll
        for (int et = 0; et < 4; ++et)
#pragma unroll
            for (int r = 0; r < 4; ++r) {
                float hv = silu_f(acc[j5][et][r] + b1v[j5]);
                h_hi[(et * 16 + g4 * 4 + r) * JP_H + (jt0 + j5) * 16 + r16] = bf16_rne(hv);
            }
    __syncthreads();

    // ---- MLP2: m[e][c], wave w owns e-tile w ----
    f32x4 acc2 = (f32x4){0.f, 0.f, 0.f, 0.f};
    {
        const unsigned short* w2h = &w2t[r16 * JP_H];
        const unsigned short* w2l = &w2t[16 * JP_H + r16 * JP_H];
        const unsigned short* hrow = &h_hi[(w * 16 + r16) * JP_H];
#pragma unroll
        for (int kk = 0; kk < 10; ++kk) {
            const int ko = kk * 32 + g4 * 8;
            bf16x8 hf = *(const bf16x8*)&hrow[ko];
            bf16x8 wh = *(const bf16x8*)&w2h[ko];
            bf16x8 wl = *(const bf16x8*)&w2l[ko];
            acc2 = __builtin_amdgcn_mfma_f32_16x16x32_bf16(hf, wh, acc2, 0, 0, 0);
            acc2 = __builtin_amdgcn_mfma_f32_16x16x32_bf16(hf, wl, acc2, 0, 0, 0);
        }
    }
    {
        float b2v = b2[r16];
#pragma unroll
        for (int r = 0; r < 4; ++r) {
            int e = w * 16 + g4 * 4 + r;
            float m = silu_f(acc2[r] + b2v);
            mij[e][r16] = m;
            if (ge0 + e < E) atomicAdd(&m_i[(size_t)dstl[e] * 16 + r16], m);
        }
    }
    __syncthreads();

    // ---- coors MLP: silu(m @ cw1 + cb1) @ cw2 + cb2 (fp32) ----
    {
        const int tj = tid & 15, te = tid >> 4;
        const int e0 = te * 4;
        float cacc[4][4];
#pragma unroll
        for (int i = 0; i < 4; ++i)
#pragma unroll
            for (int u = 0; u < 4; ++u) cacc[i][u] = 0.f;
#pragma unroll
        for (int k = 0; k < 16; ++k) {
            float4 wvv = *(const float4*)&cw1[k * 64 + tj * 4];
#pragma unroll
            for (int i = 0; i < 4; ++i) {
                float av = mij[e0 + i][k];
                cacc[i][0] += av * wvv.x;
                cacc[i][1] += av * wvv.y;
                cacc[i][2] += av * wvv.z;
                cacc[i][3] += av * wvv.w;
            }
        }
        float4 cb1v = *(const float4*)&cb1[tj * 4];
        float4 cw2v = *(const float4*)&cw2[tj * 4];
        float cb2v = cb2[0];
#pragma unroll
        for (int i = 0; i < 4; ++i) {
            float pw = silu_f(cacc[i][0] + cb1v.x) * cw2v.x
                     + silu_f(cacc[i][1] + cb1v.y) * cw2v.y
                     + silu_f(cacc[i][2] + cb1v.z) * cw2v.z
                     + silu_f(cacc[i][3] + cb1v.w) * cw2v.w;
            pw += __shfl_xor(pw, 1, 16);
            pw += __shfl_xor(pw, 2, 16);
            pw += __shfl_xor(pw, 4, 16);
            pw += __shfl_xor(pw, 8, 16);
            if (tj == 0) relc[e0 + i][3] = pw + cb2v;
        }
    }
    __syncthreads();

    // ---- scatter coors segment sums ----
    for (int idx = tid; idx < EPB * 4; idx += 256) {
        int e = idx >> 2, c = idx & 3;
        if (ge0 + e < E) {
            int d = dstl[e];
            if (c < 3) atomicAdd(&cri[(size_t)d * 3 + c], relc[e][c]);
            else       atomicAdd(&cwi[d], relc[e][3]);
        }
    }
}

// ---------------- node kernel: 2 nodes per 256-thread block ----------------
// IN-PLACE SAFE: xin may alias xout (row-private blocks, LDS-staged reads).
__global__ __launch_bounds__(256) void node_kernel(
    const float* xin,
    const float* __restrict__ m_i,
    const float* __restrict__ cri,
    const float* __restrict__ cwi,
    const float* __restrict__ nw1, const float* __restrict__ nb1,
    const float* __restrict__ nw2, const float* __restrict__ nb2,
    float* xout, int N)
{
    __shared__ __align__(16) float nin[2][80];
    __shared__ __align__(16) float hid[2][128];
    const int half = threadIdx.x >> 7, r = threadIdx.x & 127;
    const int n = blockIdx.x * 2 + half;
    const bool on = (n < N);

    if (on) {
        if (r < 64)      nin[half][r] = xin[(size_t)n * XDIM + r];
        else if (r < 80) nin[half][r] = m_i[(size_t)n * 16 + (r - 64)];
    }
    __syncthreads();
    if (on) {
        float h = nb1[r];
#pragma unroll
        for (int k = 0; k < 80; k += 4) {
            float4 a = *(const float4*)&nin[half][k];
            h += a.x * nw1[k * 128 + r] + a.y * nw1[(k + 1) * 128 + r]
               + a.z * nw1[(k + 2) * 128 + r] + a.w * nw1[(k + 3) * 128 + r];
        }
        hid[half][r] = silu_f(h);
    }
    __syncthreads();
    if (on) {
        if (r < 64) {
            float o = nb2[r];
#pragma unroll
            for (int k = 0; k < 128; k += 4) {
                float4 a = *(const float4*)&hid[half][k];
                o += a.x * nw2[k * 64 + r] + a.y * nw2[(k + 1) * 64 + r]
                   + a.z * nw2[(k + 2) * 64 + r] + a.w * nw2[(k + 3) * 64 + r];
            }
            xout[(size_t)n * XDIM + r] = o + nin[half][r];
        } else if (r < 67) {
            int c = r - 64;
            xout[(size_t)n * XDIM + r] =
                xin[(size_t)n * XDIM + r] + cwi[n] * cri[(size_t)n * 3 + c];
        }
    }
}

extern "C" void kernel_launch(void* const* d_in, const int* in_sizes, int n_in,
                              void* d_out, int out_size, void* d_ws, size_t ws_size,
                              hipStream_t stream) {
    const float* x     = (const float*)d_in[0];
    const int*   eidx  = (const int*)d_in[1];      // int32 (harness downcasts int64)
    const float* eattr = (const float*)d_in[2];
    const float* ew1   = (const float*)d_in[3];
    const float* eb1   = (const float*)d_in[4];
    const float* ew2   = (const float*)d_in[5];
    const float* eb2   = (const float*)d_in[6];
    const float* cw1   = (const float*)d_in[7];
    const float* cb1   = (const float*)d_in[8];
    const float* cw2   = (const float*)d_in[9];
    const float* cb2   = (const float*)d_in[10];
    const float* nw1   = (const float*)d_in[11];
    const float* nb1   = (const float*)d_in[12];
    const float* nw2   = (const float*)d_in[13];
    const float* nb2   = (const float*)d_in[14];

    const int N = in_sizes[0] / XDIM;
    const int E = in_sizes[1] / 2;

    // ws: acc (N*20 f32) | w1hi | w1lo (3*JP*KP bf16 each) | w2tg (3*2*16*JP_H) | b1p (3*JP f32)
    float* acc  = (float*)d_ws;
    float* m_i  = acc;
    float* cri  = acc + (size_t)N * 16;
    float* cwi  = acc + (size_t)N * 19;
    unsigned short* w1hi = (unsigned short*)(acc + (size_t)N * 20);
    unsigned short* w1lo = w1hi + (size_t)3 * JP * KP;
    unsigned short* w2tg = w1lo + (size_t)3 * JP * KP;
    float* b1p = (float*)(w2tg + (size_t)3 * 2 * 16 * JP_H);

    float* xwork = (float*)d_out;   // all layers in place on d_out

    copy_kernel<<<2048, 256, 0, stream>>>(x, xwork, N * XDIM);
    prep_w1t<<<(3 * JP * KP + 255) / 256, 256, 0, stream>>>(ew1, w1hi, w1lo);
    prep_w2t<<<(3 * 16 * JP_H + 255) / 256, 256, 0, stream>>>(ew2, w2tg);
    prep_b1<<<(3 * JP + 255) / 256, 256, 0, stream>>>(eb1, b1p);

    for (int l = 0; l < 3; ++l) {
        zero_kernel<<<1024, 256, 0, stream>>>(acc, N * 20);
        edge_kernel<<<(E + EPB - 1) / EPB, 256, 0, stream>>>(
            xwork, eidx, eattr,
            w1hi + (size_t)l * JP * KP, w1lo + (size_t)l * JP * KP,
            b1p + (size_t)l * JP,
            w2tg + (size_t)l * 2 * 16 * JP_H,
            eb2 + (size_t)l * 16,
            cw1 + (size_t)l * 16 * 64, cb1 + (size_t)l * 64,
            cw2 + (size_t)l * 64, cb2 + l,
            m_i, cri, cwi, E, N);
        node_kernel<<<(N + 1) / 2, 256, 0, stream>>>(
            xwork, m_i, cri, cwi,
            nw1 + (size_t)l * 80 * 128, nb1 + (size_t)l * 128,
            nw2 + (size_t)l * 128 * 64, nb2 + (size_t)l * 64,
            xwork, N);
    }
}

// Round 4
// 1889.834 us; speedup vs baseline: 4.7228x; 1.5713x over previous
//
#include <hip/hip_runtime.h>
#include <hip/hip_bf16.h>

#define XDIM 67
#define EIN_D 133
#define H1 266
#define KP 160      // MLP1 K padded (133 -> 5*32)
#define KP_E 168    // ein LDS row stride (bf16; ≡40 mod 64 -> conflict-free b128)
#define JP 320      // MLP1 J padded (266 -> 20*16); also MLP2 K (10*32)
#define JP_H 328    // h / w2t row stride (bf16)
#define EPB 48      // edges per block (4 blocks/CU)

typedef __attribute__((ext_vector_type(8))) short bf16x8;
typedef __attribute__((ext_vector_type(4))) float f32x4;

__device__ __forceinline__ float silu_f(float x) { return x / (1.f + __expf(-x)); }

__device__ __forceinline__ unsigned short bf16_rne(float f) {
    unsigned int u = __float_as_uint(f);
    u += 0x7fffu + ((u >> 16) & 1u);
    return (unsigned short)(u >> 16);
}
__device__ __forceinline__ float bf16_to_f(unsigned short h) {
    return __uint_as_float(((unsigned int)h) << 16);
}
__device__ __forceinline__ void split2(float v, unsigned short& h, unsigned short& l) {
    h = bf16_rne(v);
    l = bf16_rne(v - bf16_to_f(h));
}

// ---------------- utility ----------------
__global__ void zero_kernel(float* __restrict__ p, int n) {
    int n4 = n >> 2;
    float4* p4 = (float4*)p;
    for (int i = blockIdx.x * blockDim.x + threadIdx.x; i < n4; i += gridDim.x * blockDim.x)
        p4[i] = make_float4(0.f, 0.f, 0.f, 0.f);
    if (blockIdx.x == 0 && threadIdx.x == 0)
        for (int i = n4 * 4; i < n; ++i) p[i] = 0.f;
}

__global__ void copy_kernel(const float* __restrict__ src, float* __restrict__ dst, int n) {
    int n4 = n >> 2;
    const float4* s4 = (const float4*)src;
    float4* d4 = (float4*)dst;
    for (int i = blockIdx.x * blockDim.x + threadIdx.x; i < n4; i += gridDim.x * blockDim.x)
        d4[i] = s4[i];
    if (blockIdx.x == 0 && threadIdx.x == 0)
        for (int i = n4 * 4; i < n; ++i) dst[i] = src[i];
}

// ---------------- prep: split weights into bf16 hi/lo planes ----------------
__global__ void prep_w1t(const float* __restrict__ ew1, unsigned short* __restrict__ whi,
                         unsigned short* __restrict__ wlo) {
    int idx = blockIdx.x * 256 + threadIdx.x;
    if (idx >= 3 * JP * KP) return;
    int l = idx / (JP * KP);
    int rem = idx - l * JP * KP;
    int j = rem / KP, k = rem - (rem / KP) * KP;
    float w = (j < H1 && k < EIN_D) ? ew1[((size_t)l * EIN_D + k) * H1 + j] : 0.f;
    unsigned short h = bf16_rne(w);
    whi[idx] = h;
    wlo[idx] = bf16_rne(w - bf16_to_f(h));
}

// w2t: [l][2 planes][16 c][JP_H j]
__global__ void prep_w2t(const float* __restrict__ ew2, unsigned short* __restrict__ w2tg) {
    int idx = blockIdx.x * 256 + threadIdx.x;
    if (idx >= 3 * 16 * JP_H) return;
    int l = idx / (16 * JP_H);
    int rem = idx - l * 16 * JP_H;
    int c = rem / JP_H, j = rem - (rem / JP_H) * JP_H;
    float w = (j < H1) ? ew2[((size_t)l * H1 + j) * 16 + c] : 0.f;
    unsigned short h = bf16_rne(w);
    w2tg[((size_t)l * 2 + 0) * 16 * JP_H + c * JP_H + j] = h;
    w2tg[((size_t)l * 2 + 1) * 16 * JP_H + c * JP_H + j] = bf16_rne(w - bf16_to_f(h));
}

__global__ void prep_b1(const float* __restrict__ b1, float* __restrict__ b1p) {
    int idx = blockIdx.x * 256 + threadIdx.x;
    if (idx >= 3 * JP) return;
    int l = idx / JP, j = idx - (idx / JP) * JP;
    b1p[idx] = (j < H1) ? b1[l * H1 + j] : 0.f;
}

// ---------------- fused edge kernel (MFMA, 48 edges/block, 4 waves) ----------------
// MLP1: C[48e][320j] = ein[48e][160k] @ w1t^T ; wave w owns j-tiles [w*5, w*5+5)
// MLP2: m[48e][16c]  = h[48e][320j] @ w2 ; wave w (w<3) owns e-tile w
__global__ __launch_bounds__(256, 4) void edge_kernel(
    const float* __restrict__ x,
    const int* __restrict__ eidx,
    const float* __restrict__ eattr,
    const unsigned short* __restrict__ w1hi,   // [JP][KP] layer slice
    const unsigned short* __restrict__ w1lo,
    const float* __restrict__ b1p,             // [JP]
    const unsigned short* __restrict__ w2tg,   // [2][16][JP_H] layer slice
    const float* __restrict__ b2,              // [16]
    const float* __restrict__ cw1, const float* __restrict__ cb1,
    const float* __restrict__ cw2, const float* __restrict__ cb2,
    float* __restrict__ m_i, float* __restrict__ cri, float* __restrict__ cwi,
    int E, int N)
{
    // ein hi|lo planes; after MLP1 the same space holds h (bf16 hi)
    __shared__ __align__(16) unsigned short uA[2 * EPB * KP_E];   // 32256 B
    __shared__ float mij[EPB][17];
    __shared__ float relc[EPB][4];
    __shared__ int dstl[EPB];
    __shared__ int srcl[EPB];

    unsigned short* ein_hi = uA;
    unsigned short* ein_lo = uA + EPB * KP_E;
    unsigned short* h_hi   = uA;      // EPB*JP_H = 15744 u16 <= 16128 ok

    const int tid = threadIdx.x;
    const int lane = tid & 63;
    const int w = tid >> 6;
    const int ge0 = blockIdx.x * EPB;

    // ---- phase A: indices, attrs, dist, zero-pad ----
    if (tid < EPB) {
        int e = tid, ge = ge0 + e;
        if (ge < E) {
            int s = eidx[ge];
            int d = eidx[E + ge];
            dstl[e] = d; srcl[e] = s;
            const float* xs = x + (size_t)s * XDIM;
            const float* xd = x + (size_t)d * XDIM;
            float r0 = xs[64] - xd[64], r1 = xs[65] - xd[65], r2 = xs[66] - xd[66];
            relc[e][0] = r0; relc[e][1] = r1; relc[e][2] = r2;
            float dist = r0 * r0 + r1 * r1 + r2 * r2;
            unsigned short hh, hl;
            split2(dist, hh, hl);
            ein_hi[e * KP_E + 132] = hh;
            ein_lo[e * KP_E + 132] = hl;
        } else {
            dstl[e] = 0; srcl[e] = 0;
            relc[e][0] = relc[e][1] = relc[e][2] = 0.f;
            ein_hi[e * KP_E + 132] = 0;
            ein_lo[e * KP_E + 132] = 0;
        }
    }
    if (tid >= 64) {               // 192 slots: eattr split
        int t = tid - 64;
        int e = t >> 2, c = t & 3, ge = ge0 + e;
        float a = (ge < E) ? eattr[(size_t)ge * 4 + c] : 0.f;
        unsigned short hh, hl;
        split2(a, hh, hl);
        ein_hi[e * KP_E + 128 + c] = hh;
        ein_lo[e * KP_E + 128 + c] = hl;
    }
    for (int t = tid; t < EPB * 27; t += 256) {   // zero cols 133..159
        int e = t / 27, c = 133 + (t - (t / 27) * 27);
        ein_hi[e * KP_E + c] = 0;
        ein_lo[e * KP_E + c] = 0;
    }
    __syncthreads();

    // ---- gather feats: 16 lanes/row x 4 cols, 4 rows per iter ----
    {
        const int rquad = lane >> 4;
        const int c0 = (lane & 15) * 4;
        const int ebase = w * 12;
#pragma unroll
        for (int q = 0; q < 3; ++q) {
            int er = ebase + q * 4 + rquad;
            int nd = dstl[er];
            int ns = srcl[er];
            const float* xdr = x + (size_t)nd * XDIM;
            const float* xsr = x + (size_t)ns * XDIM;
            ushort4 dh, dl, sh, sl;
            split2(xdr[c0 + 0], dh.x, dl.x);
            split2(xdr[c0 + 1], dh.y, dl.y);
            split2(xdr[c0 + 2], dh.z, dl.z);
            split2(xdr[c0 + 3], dh.w, dl.w);
            split2(xsr[c0 + 0], sh.x, sl.x);
            split2(xsr[c0 + 1], sh.y, sl.y);
            split2(xsr[c0 + 2], sh.z, sl.z);
            split2(xsr[c0 + 3], sh.w, sl.w);
            *(ushort4*)&ein_hi[er * KP_E + c0]      = dh;
            *(ushort4*)&ein_lo[er * KP_E + c0]      = dl;
            *(ushort4*)&ein_hi[er * KP_E + 64 + c0] = sh;
            *(ushort4*)&ein_lo[er * KP_E + 64 + c0] = sl;
        }
    }
    __syncthreads();

    const int r16 = lane & 15, g4 = lane >> 4;
    const int jt0 = w * 5;

    // ---- MLP1: bf16x3 MFMA ----
    f32x4 acc[5][3];
#pragma unroll
    for (int a = 0; a < 5; ++a)
#pragma unroll
        for (int b = 0; b < 3; ++b) acc[a][b] = (f32x4){0.f, 0.f, 0.f, 0.f};

#pragma unroll
    for (int kk = 0; kk < 5; ++kk) {
        const int ko = kk * 32 + g4 * 8;
        bf16x8 ah[3], al[3];
#pragma unroll
        for (int et = 0; et < 3; ++et) {
            ah[et] = *(const bf16x8*)&ein_hi[(et * 16 + r16) * KP_E + ko];
            al[et] = *(const bf16x8*)&ein_lo[(et * 16 + r16) * KP_E + ko];
        }
#pragma unroll
        for (int j5 = 0; j5 < 5; ++j5) {
            const size_t wo = (size_t)((jt0 + j5) * 16 + r16) * KP + ko;
            bf16x8 bh = *(const bf16x8*)&w1hi[wo];
            bf16x8 bl = *(const bf16x8*)&w1lo[wo];
#pragma unroll
            for (int et = 0; et < 3; ++et) {
                acc[j5][et] = __builtin_amdgcn_mfma_f32_16x16x32_bf16(ah[et], bh, acc[j5][et], 0, 0, 0);
                acc[j5][et] = __builtin_amdgcn_mfma_f32_16x16x32_bf16(al[et], bh, acc[j5][et], 0, 0, 0);
                acc[j5][et] = __builtin_amdgcn_mfma_f32_16x16x32_bf16(ah[et], bl, acc[j5][et], 0, 0, 0);
            }
        }
    }

    // ---- bias + silu -> h (bf16 hi) into the union buffer ----
    float b1v[5];
#pragma unroll
    for (int j5 = 0; j5 < 5; ++j5) b1v[j5] = b1p[(jt0 + j5) * 16 + r16];

    __syncthreads();   // all ein reads done before overwrite

#pragma unroll
    for (int j5 = 0; j5 < 5; ++j5)
#pragma unroll
        for (int et = 0; et < 3; ++et)
#pragma unroll
            for (int r = 0; r < 4; ++r) {
                float hv = silu_f(acc[j5][et][r] + b1v[j5]);
                h_hi[(et * 16 + g4 * 4 + r) * JP_H + (jt0 + j5) * 16 + r16] = bf16_rne(hv);
            }
    __syncthreads();

    // ---- MLP2: m[e][c]; waves 0..2 own e-tiles; w2 frags from global ----
    if (w < 3) {
        f32x4 acc2 = (f32x4){0.f, 0.f, 0.f, 0.f};
        const unsigned short* hrow = &h_hi[(w * 16 + r16) * JP_H];
        const unsigned short* w2h = &w2tg[(size_t)r16 * JP_H];
        const unsigned short* w2l = &w2tg[(size_t)(16 + r16) * JP_H];
#pragma unroll
        for (int kk = 0; kk < 10; ++kk) {
            const int ko = kk * 32 + g4 * 8;
            bf16x8 hf = *(const bf16x8*)&hrow[ko];
            bf16x8 wh = *(const bf16x8*)&w2h[ko];
            bf16x8 wl = *(const bf16x8*)&w2l[ko];
            acc2 = __builtin_amdgcn_mfma_f32_16x16x32_bf16(hf, wh, acc2, 0, 0, 0);
            acc2 = __builtin_amdgcn_mfma_f32_16x16x32_bf16(hf, wl, acc2, 0, 0, 0);
        }
        float b2v = b2[r16];
#pragma unroll
        for (int r = 0; r < 4; ++r) {
            int e = w * 16 + g4 * 4 + r;
            float m = silu_f(acc2[r] + b2v);
            mij[e][r16] = m;
            if (ge0 + e < E) atomicAdd(&m_i[(size_t)dstl[e] * 16 + r16], m);
        }
    }
    __syncthreads();

    // ---- coors MLP: 16 groups x 3 edges ----
    {
        const int tj = tid & 15, te = tid >> 4;
        const int e0c = te * 3;
        float cacc[3][4];
#pragma unroll
        for (int i = 0; i < 3; ++i)
#pragma unroll
            for (int u = 0; u < 4; ++u) cacc[i][u] = 0.f;
#pragma unroll
        for (int k = 0; k < 16; ++k) {
            float4 wvv = *(const float4*)&cw1[k * 64 + tj * 4];
#pragma unroll
            for (int i = 0; i < 3; ++i) {
                float av = mij[e0c + i][k];
                cacc[i][0] += av * wvv.x;
                cacc[i][1] += av * wvv.y;
                cacc[i][2] += av * wvv.z;
                cacc[i][3] += av * wvv.w;
            }
        }
        float4 cb1v = *(const float4*)&cb1[tj * 4];
        float4 cw2v = *(const float4*)&cw2[tj * 4];
        float cb2v = cb2[0];
#pragma unroll
        for (int i = 0; i < 3; ++i) {
            float pw = silu_f(cacc[i][0] + cb1v.x) * cw2v.x
                     + silu_f(cacc[i][1] + cb1v.y) * cw2v.y
                     + silu_f(cacc[i][2] + cb1v.z) * cw2v.z
                     + silu_f(cacc[i][3] + cb1v.w) * cw2v.w;
            pw += __shfl_xor(pw, 1, 16);
            pw += __shfl_xor(pw, 2, 16);
            pw += __shfl_xor(pw, 4, 16);
            pw += __shfl_xor(pw, 8, 16);
            if (tj == 0) relc[e0c + i][3] = pw + cb2v;
        }
    }
    __syncthreads();

    // ---- scatter coors segment sums ----
    if (tid < EPB * 4) {
        int e = tid >> 2, c = tid & 3;
        if (ge0 + e < E) {
            int d = dstl[e];
            if (c < 3) atomicAdd(&cri[(size_t)d * 3 + c], relc[e][c]);
            else       atomicAdd(&cwi[d], relc[e][3]);
        }
    }
}

// ---------------- node kernel: 2 nodes per 256-thread block ----------------
// IN-PLACE SAFE: xin may alias xout (row-private blocks, LDS-staged reads).
__global__ __launch_bounds__(256) void node_kernel(
    const float* xin,
    const float* __restrict__ m_i,
    const float* __restrict__ cri,
    const float* __restrict__ cwi,
    const float* __restrict__ nw1, const float* __restrict__ nb1,
    const float* __restrict__ nw2, const float* __restrict__ nb2,
    float* xout, int N)
{
    __shared__ __align__(16) float nin[2][80];
    __shared__ __align__(16) float hid[2][128];
    const int half = threadIdx.x >> 7, r = threadIdx.x & 127;
    const int n = blockIdx.x * 2 + half;
    const bool on = (n < N);

    if (on) {
        if (r < 64)      nin[half][r] = xin[(size_t)n * XDIM + r];
        else if (r < 80) nin[half][r] = m_i[(size_t)n * 16 + (r - 64)];
    }
    __syncthreads();
    if (on) {
        float h = nb1[r];
#pragma unroll
        for (int k = 0; k < 80; k += 4) {
            float4 a = *(const float4*)&nin[half][k];
            h += a.x * nw1[k * 128 + r] + a.y * nw1[(k + 1) * 128 + r]
               + a.z * nw1[(k + 2) * 128 + r] + a.w * nw1[(k + 3) * 128 + r];
        }
        hid[half][r] = silu_f(h);
    }
    __syncthreads();
    if (on) {
        if (r < 64) {
            float o = nb2[r];
#pragma unroll
            for (int k = 0; k < 128; k += 4) {
                float4 a = *(const float4*)&hid[half][k];
                o += a.x * nw2[k * 64 + r] + a.y * nw2[(k + 1) * 64 + r]
                   + a.z * nw2[(k + 2) * 64 + r] + a.w * nw2[(k + 3) * 64 + r];
            }
            xout[(size_t)n * XDIM + r] = o + nin[half][r];
        } else if (r < 67) {
            int c = r - 64;
            xout[(size_t)n * XDIM + r] =
                xin[(size_t)n * XDIM + r] + cwi[n] * cri[(size_t)n * 3 + c];
        }
    }
}

extern "C" void kernel_launch(void* const* d_in, const int* in_sizes, int n_in,
                              void* d_out, int out_size, void* d_ws, size_t ws_size,
                              hipStream_t stream) {
    const float* x     = (const float*)d_in[0];
    const int*   eidx  = (const int*)d_in[1];      // int32 (harness downcasts int64)
    const float* eattr = (const float*)d_in[2];
    const float* ew1   = (const float*)d_in[3];
    const float* eb1   = (const float*)d_in[4];
    const float* ew2   = (const float*)d_in[5];
    const float* eb2   = (const float*)d_in[6];
    const float* cw1   = (const float*)d_in[7];
    const float* cb1   = (const float*)d_in[8];
    const float* cw2   = (const float*)d_in[9];
    const float* cb2   = (const float*)d_in[10];
    const float* nw1   = (const float*)d_in[11];
    const float* nb1   = (const float*)d_in[12];
    const float* nw2   = (const float*)d_in[13];
    const float* nb2   = (const float*)d_in[14];

    const int N = in_sizes[0] / XDIM;
    const int E = in_sizes[1] / 2;

    // ws: acc (N*20 f32) | w1hi | w1lo (3*JP*KP bf16 each) | w2tg (3*2*16*JP_H) | b1p (3*JP f32)
    float* acc  = (float*)d_ws;
    float* m_i  = acc;
    float* cri  = acc + (size_t)N * 16;
    float* cwi  = acc + (size_t)N * 19;
    unsigned short* w1hi = (unsigned short*)(acc + (size_t)N * 20);
    unsigned short* w1lo = w1hi + (size_t)3 * JP * KP;
    unsigned short* w2tg = w1lo + (size_t)3 * JP * KP;
    float* b1p = (float*)(w2tg + (size_t)3 * 2 * 16 * JP_H);

    float* xwork = (float*)d_out;   // all layers in place on d_out

    copy_kernel<<<2048, 256, 0, stream>>>(x, xwork, N * XDIM);
    prep_w1t<<<(3 * JP * KP + 255) / 256, 256, 0, stream>>>(ew1, w1hi, w1lo);
    prep_w2t<<<(3 * 16 * JP_H + 255) / 256, 256, 0, stream>>>(ew2, w2tg);
    prep_b1<<<(3 * JP + 255) / 256, 256, 0, stream>>>(eb1, b1p);

    for (int l = 0; l < 3; ++l) {
        zero_kernel<<<1024, 256, 0, stream>>>(acc, N * 20);
        edge_kernel<<<(E + EPB - 1) / EPB, 256, 0, stream>>>(
            xwork, eidx, eattr,
            w1hi + (size_t)l * JP * KP, w1lo + (size_t)l * JP * KP,
            b1p + (size_t)l * JP,
            w2tg + (size_t)l * 2 * 16 * JP_H,
            eb2 + (size_t)l * 16,
            cw1 + (size_t)l * 16 * 64, cb1 + (size_t)l * 64,
            cw2 + (size_t)l * 64, cb2 + l,
            m_i, cri, cwi, E, N);
        node_kernel<<<(N + 1) / 2, 256, 0, stream>>>(
            xwork, m_i, cri, cwi,
            nw1 + (size_t)l * 80 * 128, nb1 + (size_t)l * 128,
            nw2 + (size_t)l * 128 * 64, nb2 + (size_t)l * 64,
            xwork, N);
    }
}

// Round 5
// 1807.317 us; speedup vs baseline: 4.9384x; 1.0457x over previous
//
#include <hip/hip_runtime.h>
#include <hip/hip_bf16.h>

#define XDIM 67
#define EIN_D 133
#define H1 266
#define KP 160      // MLP1 K padded (133 -> 5*32)
#define KP_E 168    // ein LDS row stride (u16)
#define JP 320      // MLP1 J padded (266 -> 20*16); MLP2 K
#define JP_H 328    // h row stride (u16)
#define MSTR 40     // mij_bf row stride (u16), K-padded 16->32 (+8 align)
#define EPB 48      // edges per block

typedef __attribute__((ext_vector_type(8))) short bf16x8;
typedef __attribute__((ext_vector_type(4))) float f32x4;
typedef __attribute__((ext_vector_type(2))) float f32x2;
typedef __attribute__((ext_vector_type(2))) __bf16 b16x2;

__device__ __forceinline__ float silu_f(float x) { return x / (1.f + __expf(-x)); }

__device__ __forceinline__ unsigned short bf16_rne(float f) {
    unsigned int u = __float_as_uint(f);
    u += 0x7fffu + ((u >> 16) & 1u);
    return (unsigned short)(u >> 16);
}
__device__ __forceinline__ float bf16_to_f(unsigned short h) {
    return __uint_as_float(((unsigned int)h) << 16);
}
// pack two floats -> two bf16 in one u32 (v_cvt_pk_bf16_f32 on gfx950); a in low half
__device__ __forceinline__ unsigned int packbf2(float a, float b) {
    b16x2 c = __builtin_convertvector((f32x2){a, b}, b16x2);
    unsigned int u; __builtin_memcpy(&u, &c, 4); return u;
}

// ---------------- utility: copy x to out + zero accumulators ----------------
__global__ void copy_zero_kernel(const float* __restrict__ src, float* __restrict__ dst,
                                 int n, float* __restrict__ z, int nz) {
    int n4 = n >> 2, nz4 = nz >> 2;
    const float4* s4 = (const float4*)src;
    float4* d4 = (float4*)dst;
    float4* z4 = (float4*)z;
    for (int i = blockIdx.x * blockDim.x + threadIdx.x; i < n4; i += gridDim.x * blockDim.x)
        d4[i] = s4[i];
    for (int i = blockIdx.x * blockDim.x + threadIdx.x; i < nz4; i += gridDim.x * blockDim.x)
        z4[i] = make_float4(0.f, 0.f, 0.f, 0.f);
    if (blockIdx.x == 0 && threadIdx.x == 0) {
        for (int i = n4 * 4; i < n; ++i) dst[i] = src[i];
        for (int i = nz4 * 4; i < nz; ++i) z[i] = 0.f;
    }
}

// ---------------- prep: split weights into bf16 hi/lo planes ----------------
__global__ void prep_w1t(const float* __restrict__ ew1, unsigned short* __restrict__ whi,
                         unsigned short* __restrict__ wlo) {
    int idx = blockIdx.x * 256 + threadIdx.x;
    if (idx >= 3 * JP * KP) return;
    int l = idx / (JP * KP);
    int rem = idx - l * JP * KP;
    int j = rem / KP, k = rem - (rem / KP) * KP;
    float w = (j < H1 && k < EIN_D) ? ew1[((size_t)l * EIN_D + k) * H1 + j] : 0.f;
    unsigned short h = bf16_rne(w);
    whi[idx] = h;
    wlo[idx] = bf16_rne(w - bf16_to_f(h));
}

__global__ void prep_w2t(const float* __restrict__ ew2, unsigned short* __restrict__ w2tg) {
    int idx = blockIdx.x * 256 + threadIdx.x;
    if (idx >= 3 * 16 * JP_H) return;
    int l = idx / (16 * JP_H);
    int rem = idx - l * 16 * JP_H;
    int c = rem / JP_H, j = rem - (rem / JP_H) * JP_H;
    float w = (j < H1) ? ew2[((size_t)l * H1 + j) * 16 + c] : 0.f;
    unsigned short h = bf16_rne(w);
    w2tg[((size_t)l * 2 + 0) * 16 * JP_H + c * JP_H + j] = h;
    w2tg[((size_t)l * 2 + 1) * 16 * JP_H + c * JP_H + j] = bf16_rne(w - bf16_to_f(h));
}

__global__ void prep_b1(const float* __restrict__ b1, float* __restrict__ b1p) {
    int idx = blockIdx.x * 256 + threadIdx.x;
    if (idx >= 3 * JP) return;
    int l = idx / JP, j = idx - (idx / JP) * JP;
    b1p[idx] = (j < H1) ? b1[l * H1 + j] : 0.f;
}

// cw1t: [l][64 j][32 c] bf16, c>=16 zero (K pad for 16x16x32 mfma)
__global__ void prep_cw1t(const float* __restrict__ cw1, unsigned short* __restrict__ cw1t) {
    int idx = blockIdx.x * 256 + threadIdx.x;
    if (idx >= 3 * 64 * 32) return;
    int l = idx / (64 * 32);
    int rem = idx - l * 64 * 32;
    int j = rem >> 5, c = rem & 31;
    cw1t[idx] = (c < 16) ? bf16_rne(cw1[(size_t)l * 16 * 64 + c * 64 + j]) : (unsigned short)0;
}

// ---------------- fused edge kernel (MFMA, 48 edges/block, 4 waves) ----------------
// MLP1 (operand-swapped): D[j][e] = w1t x ein ; wave w owns j-tiles [w*5, w*5+5)
// MLP2: m[e][c] = h x w2 ; waves 0..2 own e-tiles; coors MLP1 on MFMA too.
__global__ __launch_bounds__(256, 4) void edge_kernel(
    const float* __restrict__ x,
    const int* __restrict__ eidx,
    const float* __restrict__ eattr,
    const unsigned short* __restrict__ w1hi,   // [JP][KP] layer slice
    const unsigned short* __restrict__ w1lo,
    const float* __restrict__ b1p,             // [JP]
    const unsigned short* __restrict__ w2tg,   // [2][16][JP_H] layer slice
    const float* __restrict__ b2,              // [16]
    const unsigned short* __restrict__ cw1t,   // [64][32] bf16 layer slice
    const float* __restrict__ cb1,
    const float* __restrict__ cw2, const float* __restrict__ cb2,
    float* __restrict__ m_i, float* __restrict__ cri, float* __restrict__ cwi,
    int E, int N)
{
    __shared__ __align__(16) unsigned short uA[2 * EPB * KP_E];   // 32256 B
    __shared__ __align__(16) unsigned short mij_bf[EPB * MSTR];   // 3840 B
    __shared__ float relc[EPB][4];
    __shared__ int dstl[EPB], srcl[EPB];

    unsigned short* ein_hi = uA;
    unsigned short* ein_lo = uA + EPB * KP_E;
    unsigned short* h_hi   = uA;      // 48*328 = 15744 u16 <= 16128 ok

    const int tid = threadIdx.x;
    const int lane = tid & 63;
    const int w = tid >> 6;
    const int ge0 = blockIdx.x * EPB;
    const int r16 = lane & 15, g4 = lane >> 4;

    // ---- phase A: indices, dist, attrs, pads ----
    if (tid < EPB) {
        int e = tid, ge = ge0 + e;
        if (ge < E) {
            int s = eidx[ge];
            int d = eidx[E + ge];
            dstl[e] = d; srcl[e] = s;
            const float* xs = x + (size_t)s * XDIM;
            const float* xd = x + (size_t)d * XDIM;
            float r0 = xs[64] - xd[64], r1 = xs[65] - xd[65], r2 = xs[66] - xd[66];
            relc[e][0] = r0; relc[e][1] = r1; relc[e][2] = r2;
            float dist = r0 * r0 + r1 * r1 + r2 * r2;
            unsigned short hh = bf16_rne(dist);
            ein_hi[e * KP_E + 132] = hh;
            ein_lo[e * KP_E + 132] = bf16_rne(dist - bf16_to_f(hh));
        } else {
            dstl[e] = 0; srcl[e] = 0;
            relc[e][0] = relc[e][1] = relc[e][2] = 0.f;
            ein_hi[e * KP_E + 132] = 0;
            ein_lo[e * KP_E + 132] = 0;
        }
    }
    if (tid >= 64) {               // 192 slots: eattr split
        int t = tid - 64;
        int e = t >> 2, c = t & 3, ge = ge0 + e;
        float a = (ge < E) ? eattr[(size_t)ge * 4 + c] : 0.f;
        unsigned short hh = bf16_rne(a);
        ein_hi[e * KP_E + 128 + c] = hh;
        ein_lo[e * KP_E + 128 + c] = bf16_rne(a - bf16_to_f(hh));
    }
    for (int t = tid; t < EPB * 27; t += 256) {   // zero k cols 133..159
        int e = t / 27, c = 133 + (t - (t / 27) * 27);
        ein_hi[e * KP_E + c] = 0;
        ein_lo[e * KP_E + c] = 0;
    }
    if (tid < 192) {               // zero mij_bf K-pad cols 16..31
        int e = tid >> 2, q = tid & 3;
        uint2 zz; zz.x = 0u; zz.y = 0u;
        *(uint2*)&mij_bf[e * MSTR + 16 + q * 4] = zz;
    }
    __syncthreads();

    // ---- gather feats: 16 lanes/row x 4 cols, 4 rows/iter ----
    {
        const int rquad = g4;
        const int c0 = r16 * 4;
        const int ebase = w * 12;
#pragma unroll
        for (int q = 0; q < 3; ++q) {
            int er = ebase + q * 4 + rquad;
            const float* xdr = x + (size_t)dstl[er] * XDIM;
            const float* xsr = x + (size_t)srcl[er] * XDIM;
            float d0 = xdr[c0], d1 = xdr[c0 + 1], d2 = xdr[c0 + 2], d3 = xdr[c0 + 3];
            float s0 = xsr[c0], s1 = xsr[c0 + 1], s2 = xsr[c0 + 2], s3 = xsr[c0 + 3];
            unsigned int dh01 = packbf2(d0, d1), dh23 = packbf2(d2, d3);
            unsigned int sh01 = packbf2(s0, s1), sh23 = packbf2(s2, s3);
            float dl0 = d0 - __uint_as_float(dh01 << 16);
            float dl1 = d1 - __uint_as_float(dh01 & 0xffff0000u);
            float dl2 = d2 - __uint_as_float(dh23 << 16);
            float dl3 = d3 - __uint_as_float(dh23 & 0xffff0000u);
            float sl0 = s0 - __uint_as_float(sh01 << 16);
            float sl1 = s1 - __uint_as_float(sh01 & 0xffff0000u);
            float sl2 = s2 - __uint_as_float(sh23 << 16);
            float sl3 = s3 - __uint_as_float(sh23 & 0xffff0000u);
            uint2 vh, vl;
            vh.x = dh01; vh.y = dh23;
            vl.x = packbf2(dl0, dl1); vl.y = packbf2(dl2, dl3);
            *(uint2*)&ein_hi[er * KP_E + c0] = vh;
            *(uint2*)&ein_lo[er * KP_E + c0] = vl;
            vh.x = sh01; vh.y = sh23;
            vl.x = packbf2(sl0, sl1); vl.y = packbf2(sl2, sl3);
            *(uint2*)&ein_hi[er * KP_E + 64 + c0] = vh;
            *(uint2*)&ein_lo[er * KP_E + 64 + c0] = vl;
        }
    }
    __syncthreads();

    const int jt0 = w * 5;

    // ---- MLP1: bf16x3, operand-swapped: D[j][e] ----
    f32x4 acc[5][3];
#pragma unroll
    for (int a = 0; a < 5; ++a)
#pragma unroll
        for (int b = 0; b < 3; ++b) acc[a][b] = (f32x4){0.f, 0.f, 0.f, 0.f};

#pragma unroll
    for (int kk = 0; kk < 5; ++kk) {
        const int ko = kk * 32 + g4 * 8;
        bf16x8 ah[3], al[3];
#pragma unroll
        for (int et = 0; et < 3; ++et) {
            ah[et] = *(const bf16x8*)&ein_hi[(et * 16 + r16) * KP_E + ko];
            al[et] = *(const bf16x8*)&ein_lo[(et * 16 + r16) * KP_E + ko];
        }
#pragma unroll
        for (int j5 = 0; j5 < 5; ++j5) {
            const size_t wo = (size_t)((jt0 + j5) * 16 + r16) * KP + ko;
            bf16x8 bh = *(const bf16x8*)&w1hi[wo];
            bf16x8 bl = *(const bf16x8*)&w1lo[wo];
#pragma unroll
            for (int et = 0; et < 3; ++et) {
                acc[j5][et] = __builtin_amdgcn_mfma_f32_16x16x32_bf16(bh, ah[et], acc[j5][et], 0, 0, 0);
                acc[j5][et] = __builtin_amdgcn_mfma_f32_16x16x32_bf16(bl, ah[et], acc[j5][et], 0, 0, 0);
                acc[j5][et] = __builtin_amdgcn_mfma_f32_16x16x32_bf16(bh, al[et], acc[j5][et], 0, 0, 0);
            }
        }
    }

    // D[j][e]: j = (jt0+j5)*16 + g4*4 + r, e = et*16 + r16
    float4 b1v[5];
#pragma unroll
    for (int j5 = 0; j5 < 5; ++j5)
        b1v[j5] = *(const float4*)&b1p[(jt0 + j5) * 16 + g4 * 4];

    __syncthreads();   // all ein reads done before h overwrite

#pragma unroll
    for (int j5 = 0; j5 < 5; ++j5) {
#pragma unroll
        for (int et = 0; et < 3; ++et) {
            f32x4 a = acc[j5][et];
            float h0 = silu_f(a[0] + b1v[j5].x);
            float h1 = silu_f(a[1] + b1v[j5].y);
            float h2 = silu_f(a[2] + b1v[j5].z);
            float h3 = silu_f(a[3] + b1v[j5].w);
            uint2 uu;
            uu.x = packbf2(h0, h1);
            uu.y = packbf2(h2, h3);
            *(uint2*)&h_hi[(et * 16 + r16) * JP_H + (jt0 + j5) * 16 + g4 * 4] = uu;
        }
    }
    __syncthreads();

    // ---- MLP2: m[e][c]; waves 0..2; w2 frags from global ----
    if (w < 3) {
        f32x4 acc2 = (f32x4){0.f, 0.f, 0.f, 0.f};
        const unsigned short* hrow = &h_hi[(w * 16 + r16) * JP_H];
        const unsigned short* w2h = &w2tg[(size_t)r16 * JP_H];
        const unsigned short* w2l = &w2tg[(size_t)(16 + r16) * JP_H];
#pragma unroll
        for (int kk = 0; kk < 10; ++kk) {
            const int ko = kk * 32 + g4 * 8;
            bf16x8 hf = *(const bf16x8*)&hrow[ko];
            bf16x8 wh = *(const bf16x8*)&w2h[ko];
            bf16x8 wl = *(const bf16x8*)&w2l[ko];
            acc2 = __builtin_amdgcn_mfma_f32_16x16x32_bf16(hf, wh, acc2, 0, 0, 0);
            acc2 = __builtin_amdgcn_mfma_f32_16x16x32_bf16(hf, wl, acc2, 0, 0, 0);
        }
        float b2v = b2[r16];
#pragma unroll
        for (int r = 0; r < 4; ++r) {
            int e = w * 16 + g4 * 4 + r;
            float m = silu_f(acc2[r] + b2v);
            mij_bf[e * MSTR + r16] = bf16_rne(m);
            if (ge0 + e < E) atomicAdd(&m_i[(size_t)dstl[e] * 16 + r16], m);
        }
    }
    __syncthreads();

    // ---- coors MLP on MFMA: coor_h[48e][64j] = m[48][16pad32] @ cw1t^T ----
    if (w < 3) {
        bf16x8 afrag = *(const bf16x8*)&mij_bf[(w * 16 + r16) * MSTR + g4 * 8];
        f32x4 cacc[4];
#pragma unroll
        for (int jt = 0; jt < 4; ++jt) {
            bf16x8 bfrag = *(const bf16x8*)&cw1t[(jt * 16 + r16) * 32 + g4 * 8];
            cacc[jt] = __builtin_amdgcn_mfma_f32_16x16x32_bf16(afrag, bfrag,
                        (f32x4){0.f, 0.f, 0.f, 0.f}, 0, 0, 0);
        }
        // D[e][j]: e = w*16 + g4*4 + r, j = jt*16 + r16
        float pw0 = 0.f, pw1 = 0.f, pw2 = 0.f, pw3 = 0.f;
#pragma unroll
        for (int jt = 0; jt < 4; ++jt) {
            float cb = cb1[jt * 16 + r16];
            float cw = cw2[jt * 16 + r16];
            pw0 += silu_f(cacc[jt][0] + cb) * cw;
            pw1 += silu_f(cacc[jt][1] + cb) * cw;
            pw2 += silu_f(cacc[jt][2] + cb) * cw;
            pw3 += silu_f(cacc[jt][3] + cb) * cw;
        }
#pragma unroll
        for (int s = 1; s < 16; s <<= 1) {
            pw0 += __shfl_xor(pw0, s, 16);
            pw1 += __shfl_xor(pw1, s, 16);
            pw2 += __shfl_xor(pw2, s, 16);
            pw3 += __shfl_xor(pw3, s, 16);
        }
        if (r16 == 0) {
            float cb2v = cb2[0];
            int e = w * 16 + g4 * 4;
            relc[e + 0][3] = pw0 + cb2v;
            relc[e + 1][3] = pw1 + cb2v;
            relc[e + 2][3] = pw2 + cb2v;
            relc[e + 3][3] = pw3 + cb2v;
        }
    }
    __syncthreads();

    // ---- scatter coors segment sums ----
    if (tid < EPB * 4) {
        int e = tid >> 2, c = tid & 3;
        if (ge0 + e < E) {
            int d = dstl[e];
            if (c < 3) atomicAdd(&cri[(size_t)d * 3 + c], relc[e][c]);
            else       atomicAdd(&cwi[d], relc[e][3]);
        }
    }
}

// ---------------- node kernel: 2 nodes per 256-thread block ----------------
// IN-PLACE SAFE (xin may alias xout). Also re-zeroes accumulators for next layer.
__global__ __launch_bounds__(256) void node_kernel(
    const float* xin,
    float* __restrict__ m_i,
    float* __restrict__ cri,
    float* __restrict__ cwi,
    const float* __restrict__ nw1, const float* __restrict__ nb1,
    const float* __restrict__ nw2, const float* __restrict__ nb2,
    float* xout, int N)
{
    __shared__ __align__(16) float nin[2][80];
    __shared__ __align__(16) float hid[2][128];
    const int half = threadIdx.x >> 7, r = threadIdx.x & 127;
    const int n = blockIdx.x * 2 + half;
    const bool on = (n < N);

    if (on) {
        if (r < 64)      nin[half][r] = xin[(size_t)n * XDIM + r];
        else if (r < 80) nin[half][r] = m_i[(size_t)n * 16 + (r - 64)];
    }
    __syncthreads();
    if (on) {
        float h = nb1[r];
#pragma unroll
        for (int k = 0; k < 80; k += 4) {
            float4 a = *(const float4*)&nin[half][k];
            h += a.x * nw1[k * 128 + r] + a.y * nw1[(k + 1) * 128 + r]
               + a.z * nw1[(k + 2) * 128 + r] + a.w * nw1[(k + 3) * 128 + r];
        }
        hid[half][r] = silu_f(h);
    }
    __syncthreads();
    if (on) {
        if (r < 64) {
            float o = nb2[r];
#pragma unroll
            for (int k = 0; k < 128; k += 4) {
                float4 a = *(const float4*)&hid[half][k];
                o += a.x * nw2[k * 64 + r] + a.y * nw2[(k + 1) * 64 + r]
                   + a.z * nw2[(k + 2) * 64 + r] + a.w * nw2[(k + 3) * 64 + r];
            }
            xout[(size_t)n * XDIM + r] = o + nin[half][r];
        } else if (r < 67) {
            int c = r - 64;
            xout[(size_t)n * XDIM + r] =
                xin[(size_t)n * XDIM + r] + cwi[n] * cri[(size_t)n * 3 + c];
        }
    }
    __syncthreads();   // all acc reads done; re-zero for next layer's atomics
    if (on) {
        if (r < 16)      m_i[(size_t)n * 16 + r] = 0.f;
        else if (r < 19) cri[(size_t)n * 3 + (r - 16)] = 0.f;
        else if (r == 19) cwi[n] = 0.f;
    }
}

extern "C" void kernel_launch(void* const* d_in, const int* in_sizes, int n_in,
                              void* d_out, int out_size, void* d_ws, size_t ws_size,
                              hipStream_t stream) {
    const float* x     = (const float*)d_in[0];
    const int*   eidx  = (const int*)d_in[1];      // int32 (harness downcasts int64)
    const float* eattr = (const float*)d_in[2];
    const float* ew1   = (const float*)d_in[3];
    const float* eb1   = (const float*)d_in[4];
    const float* ew2   = (const float*)d_in[5];
    const float* eb2   = (const float*)d_in[6];
    const float* cw1   = (const float*)d_in[7];
    const float* cb1   = (const float*)d_in[8];
    const float* cw2   = (const float*)d_in[9];
    const float* cb2   = (const float*)d_in[10];
    const float* nw1   = (const float*)d_in[11];
    const float* nb1   = (const float*)d_in[12];
    const float* nw2   = (const float*)d_in[13];
    const float* nb2   = (const float*)d_in[14];

    const int N = in_sizes[0] / XDIM;
    const int E = in_sizes[1] / 2;

    // ws: acc(N*20 f32) | b1p(3*JP f32) | w1hi | w1lo (3*JP*KP u16) | w2tg | cw1t
    float* acc  = (float*)d_ws;
    float* m_i  = acc;
    float* cri  = acc + (size_t)N * 16;
    float* cwi  = acc + (size_t)N * 19;
    float* b1p  = acc + (size_t)N * 20;
    unsigned short* w1hi = (unsigned short*)(b1p + (size_t)3 * JP);
    unsigned short* w1lo = w1hi + (size_t)3 * JP * KP;
    unsigned short* w2tg = w1lo + (size_t)3 * JP * KP;
    unsigned short* cw1t = w2tg + (size_t)3 * 2 * 16 * JP_H;

    float* xwork = (float*)d_out;   // all layers in place on d_out

    copy_zero_kernel<<<2048, 256, 0, stream>>>(x, xwork, N * XDIM, acc, N * 20);
    prep_w1t<<<(3 * JP * KP + 255) / 256, 256, 0, stream>>>(ew1, w1hi, w1lo);
    prep_w2t<<<(3 * 16 * JP_H + 255) / 256, 256, 0, stream>>>(ew2, w2tg);
    prep_b1<<<(3 * JP + 255) / 256, 256, 0, stream>>>(eb1, b1p);
    prep_cw1t<<<(3 * 64 * 32 + 255) / 256, 256, 0, stream>>>(cw1, cw1t);

    for (int l = 0; l < 3; ++l) {
        edge_kernel<<<(E + EPB - 1) / EPB, 256, 0, stream>>>(
            xwork, eidx, eattr,
            w1hi + (size_t)l * JP * KP, w1lo + (size_t)l * JP * KP,
            b1p + (size_t)l * JP,
            w2tg + (size_t)l * 2 * 16 * JP_H,
            eb2 + (size_t)l * 16,
            cw1t + (size_t)l * 64 * 32,
            cb1 + (size_t)l * 64,
            cw2 + (size_t)l * 64, cb2 + l,
            m_i, cri, cwi, E, N);
        node_kernel<<<(N + 1) / 2, 256, 0, stream>>>(
            xwork, m_i, cri, cwi,
            nw1 + (size_t)l * 80 * 128, nb1 + (size_t)l * 128,
            nw2 + (size_t)l * 128 * 64, nb2 + (size_t)l * 64,
            xwork, N);
    }
}

// Round 7
// 1760.906 us; speedup vs baseline: 5.0685x; 1.0264x over previous
//
#include <hip/hip_runtime.h>
#include <hip/hip_bf16.h>

#define XDIM 67
#define EIN_D 133
#define H1 266
#define KP 160      // MLP1 K padded (133 -> 5*32)
#define KP_E 168    // ein LDS row stride (u16)
#define JP 320      // MLP1 J padded (266 -> 20*16); MLP2 K
#define JP_H 328    // h row stride (u16)
#define MSTR 40     // mij row stride (u16), K-padded 16->32 (+8 align)
#define EPB 48      // edges per block

typedef __attribute__((ext_vector_type(8))) short bf16x8;
typedef __attribute__((ext_vector_type(4))) float f32x4;
typedef __attribute__((ext_vector_type(2))) float f32x2;
typedef __attribute__((ext_vector_type(2))) __bf16 b16x2;

__device__ __forceinline__ float silu_f(float x) {
    return x * __builtin_amdgcn_rcpf(1.f + __expf(-x));
}

__device__ __forceinline__ unsigned short bf16_rne(float f) {
    unsigned int u = __float_as_uint(f);
    u += 0x7fffu + ((u >> 16) & 1u);
    return (unsigned short)(u >> 16);
}
__device__ __forceinline__ float bf16_to_f(unsigned short h) {
    return __uint_as_float(((unsigned int)h) << 16);
}
// pack two floats -> two bf16 in one u32 (v_cvt_pk_bf16_f32); a in low half
__device__ __forceinline__ unsigned int packbf2(float a, float b) {
    b16x2 c = __builtin_convertvector((f32x2){a, b}, b16x2);
    unsigned int u; __builtin_memcpy(&u, &c, 4); return u;
}

// ---------------- utility: copy x to out + zero accumulators ----------------
__global__ void copy_zero_kernel(const float* __restrict__ src, float* __restrict__ dst,
                                 int n, float* __restrict__ z, int nz) {
    int n4 = n >> 2, nz4 = nz >> 2;
    const float4* s4 = (const float4*)src;
    float4* d4 = (float4*)dst;
    float4* z4 = (float4*)z;
    for (int i = blockIdx.x * blockDim.x + threadIdx.x; i < n4; i += gridDim.x * blockDim.x)
        d4[i] = s4[i];
    for (int i = blockIdx.x * blockDim.x + threadIdx.x; i < nz4; i += gridDim.x * blockDim.x)
        z4[i] = make_float4(0.f, 0.f, 0.f, 0.f);
    if (blockIdx.x == 0 && threadIdx.x == 0) {
        for (int i = n4 * 4; i < n; ++i) dst[i] = src[i];
        for (int i = nz4 * 4; i < nz; ++i) z[i] = 0.f;
    }
}

// ---------------- prep: split weights into bf16 hi/lo planes ----------------
__global__ void prep_w1t(const float* __restrict__ ew1, unsigned short* __restrict__ whi,
                         unsigned short* __restrict__ wlo) {
    int idx = blockIdx.x * 256 + threadIdx.x;
    if (idx >= 3 * JP * KP) return;
    int l = idx / (JP * KP);
    int rem = idx - l * JP * KP;
    int j = rem / KP, k = rem - (rem / KP) * KP;
    float w = (j < H1 && k < EIN_D) ? ew1[((size_t)l * EIN_D + k) * H1 + j] : 0.f;
    unsigned short h = bf16_rne(w);
    whi[idx] = h;
    wlo[idx] = bf16_rne(w - bf16_to_f(h));
}

__global__ void prep_w2t(const float* __restrict__ ew2, unsigned short* __restrict__ w2tg) {
    int idx = blockIdx.x * 256 + threadIdx.x;
    if (idx >= 3 * 16 * JP_H) return;
    int l = idx / (16 * JP_H);
    int rem = idx - l * 16 * JP_H;
    int c = rem / JP_H, j = rem - (rem / JP_H) * JP_H;
    float w = (j < H1) ? ew2[((size_t)l * H1 + j) * 16 + c] : 0.f;
    unsigned short h = bf16_rne(w);
    w2tg[((size_t)l * 2 + 0) * 16 * JP_H + c * JP_H + j] = h;
    w2tg[((size_t)l * 2 + 1) * 16 * JP_H + c * JP_H + j] = bf16_rne(w - bf16_to_f(h));
}

__global__ void prep_b1(const float* __restrict__ b1, float* __restrict__ b1p) {
    int idx = blockIdx.x * 256 + threadIdx.x;
    if (idx >= 3 * JP) return;
    int l = idx / JP, j = idx - (idx / JP) * JP;
    b1p[idx] = (j < H1) ? b1[l * H1 + j] : 0.f;
}

// cw1t: [l][64 j][32 c] bf16, c>=16 zero
__global__ void prep_cw1t(const float* __restrict__ cw1, unsigned short* __restrict__ cw1t) {
    int idx = blockIdx.x * 256 + threadIdx.x;
    if (idx >= 3 * 64 * 32) return;
    int l = idx / (64 * 32);
    int rem = idx - l * 64 * 32;
    int j = rem >> 5, c = rem & 31;
    cw1t[idx] = (c < 16) ? bf16_rne(cw1[(size_t)l * 16 * 64 + c * 64 + j]) : (unsigned short)0;
}

// split 8 fp32 (4 dst cols + 4 src cols) -> hi/lo bf16 and store to ein
__device__ __forceinline__ void store_feats(unsigned short* __restrict__ ein_hi,
                                            unsigned short* __restrict__ ein_lo,
                                            int er, int c0, const float* v) {
    unsigned int dh01 = packbf2(v[0], v[1]), dh23 = packbf2(v[2], v[3]);
    unsigned int sh01 = packbf2(v[4], v[5]), sh23 = packbf2(v[6], v[7]);
    float dl0 = v[0] - __uint_as_float(dh01 << 16);
    float dl1 = v[1] - __uint_as_float(dh01 & 0xffff0000u);
    float dl2 = v[2] - __uint_as_float(dh23 << 16);
    float dl3 = v[3] - __uint_as_float(dh23 & 0xffff0000u);
    float sl0 = v[4] - __uint_as_float(sh01 << 16);
    float sl1 = v[5] - __uint_as_float(sh01 & 0xffff0000u);
    float sl2 = v[6] - __uint_as_float(sh23 << 16);
    float sl3 = v[7] - __uint_as_float(sh23 & 0xffff0000u);
    uint2 u;
    u.x = dh01; u.y = dh23;
    *(uint2*)&ein_hi[er * KP_E + c0] = u;
    u.x = packbf2(dl0, dl1); u.y = packbf2(dl2, dl3);
    *(uint2*)&ein_lo[er * KP_E + c0] = u;
    u.x = sh01; u.y = sh23;
    *(uint2*)&ein_hi[er * KP_E + 64 + c0] = u;
    u.x = packbf2(sl0, sl1); u.y = packbf2(sl2, sl3);
    *(uint2*)&ein_lo[er * KP_E + 64 + c0] = u;
}

// ---------------- fused edge kernel (MFMA, 48 edges/block, 4 waves) ----------------
__global__ __launch_bounds__(256, 4) void edge_kernel(
    const float* __restrict__ x,
    const int* __restrict__ eidx,
    const float* __restrict__ eattr,
    const unsigned short* __restrict__ w1hi,   // [JP][KP] layer slice
    const unsigned short* __restrict__ w1lo,
    const float* __restrict__ b1p,             // [JP]
    const unsigned short* __restrict__ w2tg,   // [2][16][JP_H] layer slice
    const float* __restrict__ b2,              // [16]
    const unsigned short* __restrict__ cw1t,   // [64][32] bf16 layer slice
    const float* __restrict__ cb1,
    const float* __restrict__ cw2, const float* __restrict__ cb2,
    float* __restrict__ m_i, float* __restrict__ cri, float* __restrict__ cwi,
    int E, int N)
{
    __shared__ __align__(16) unsigned short uA[2 * EPB * KP_E];   // 32256 B
    __shared__ __align__(16) unsigned short mij_bf[EPB * MSTR];   // 3840 B
    __shared__ float relc[EPB][4];
    __shared__ int dstl[EPB];

    unsigned short* ein_hi = uA;
    unsigned short* ein_lo = uA + EPB * KP_E;
    unsigned short* h_hi   = uA;      // 48*328 = 15744 u16 fits in plane 0

    const int tid = threadIdx.x;
    const int lane = tid & 63;
    const int w = tid >> 6;
    const int ge0 = blockIdx.x * EPB;
    const int r16 = lane & 15, g4 = lane >> 4;

    // ======== EARLY GATHER: issue all index + feat loads up front ========
    const int c0 = r16 * 4;
    const int erA = w * 12 + g4, erB = erA + 4, erC = erA + 8;
    const int geA = ge0 + erA, geB = ge0 + erB, geC = ge0 + erC;
    const int sA = (geA < E) ? eidx[geA] : 0, dA = (geA < E) ? eidx[E + geA] : 0;
    const int sB = (geB < E) ? eidx[geB] : 0, dB = (geB < E) ? eidx[E + geB] : 0;
    const int sC = (geC < E) ? eidx[geC] : 0, dC = (geC < E) ? eidx[E + geC] : 0;
    float vA[8], vB[8], vC[8];
    {
        const float* p;
        p = x + (size_t)dA * XDIM + c0; vA[0] = p[0]; vA[1] = p[1]; vA[2] = p[2]; vA[3] = p[3];
        p = x + (size_t)sA * XDIM + c0; vA[4] = p[0]; vA[5] = p[1]; vA[6] = p[2]; vA[7] = p[3];
        p = x + (size_t)dB * XDIM + c0; vB[0] = p[0]; vB[1] = p[1]; vB[2] = p[2]; vB[3] = p[3];
        p = x + (size_t)sB * XDIM + c0; vB[4] = p[0]; vB[5] = p[1]; vB[6] = p[2]; vB[7] = p[3];
        p = x + (size_t)dC * XDIM + c0; vC[0] = p[0]; vC[1] = p[1]; vC[2] = p[2]; vC[3] = p[3];
        p = x + (size_t)sC * XDIM + c0; vC[4] = p[0]; vC[5] = p[1]; vC[6] = p[2]; vC[7] = p[3];
    }

    // ---- phase A (overlaps with in-flight gather): dist, attrs, pads ----
    if (tid < EPB) {
        int e = tid, ge = ge0 + e;
        if (ge < E) {
            int s = eidx[ge];
            int d = eidx[E + ge];
            dstl[e] = d;
            const float* xs = x + (size_t)s * XDIM;
            const float* xd = x + (size_t)d * XDIM;
            float r0 = xs[64] - xd[64], r1 = xs[65] - xd[65], r2 = xs[66] - xd[66];
            relc[e][0] = r0; relc[e][1] = r1; relc[e][2] = r2;
            float dist = r0 * r0 + r1 * r1 + r2 * r2;
            unsigned short hh = bf16_rne(dist);
            ein_hi[e * KP_E + 132] = hh;
            ein_lo[e * KP_E + 132] = bf16_rne(dist - bf16_to_f(hh));
        } else {
            dstl[e] = 0;
            relc[e][0] = relc[e][1] = relc[e][2] = 0.f;
            ein_hi[e * KP_E + 132] = 0;
            ein_lo[e * KP_E + 132] = 0;
        }
    }
    if (tid >= 64) {               // 192 slots: eattr split
        int t = tid - 64;
        int e = t >> 2, c = t & 3, ge = ge0 + e;
        float a = (ge < E) ? eattr[(size_t)ge * 4 + c] : 0.f;
        unsigned short hh = bf16_rne(a);
        ein_hi[e * KP_E + 128 + c] = hh;
        ein_lo[e * KP_E + 128 + c] = bf16_rne(a - bf16_to_f(hh));
    }
    for (int t = tid; t < EPB * 27; t += 256) {   // zero k cols 133..159
        int e = t / 27, c = 133 + (t - (t / 27) * 27);
        ein_hi[e * KP_E + c] = 0;
        ein_lo[e * KP_E + c] = 0;
    }
    if (tid < 192) {               // zero mij K-pad cols 16..31
        int e = tid >> 2, q = tid & 3;
        uint2 zz; zz.x = 0u; zz.y = 0u;
        *(uint2*)&mij_bf[e * MSTR + 16 + q * 4] = zz;
    }

    // ---- consume gather results (loads have had time in flight) ----
    store_feats(ein_hi, ein_lo, erA, c0, vA);
    store_feats(ein_hi, ein_lo, erB, c0, vB);
    store_feats(ein_hi, ein_lo, erC, c0, vC);
    __syncthreads();

    const int jt0 = w * 5;

    // ---- MLP1: bf16x3, operand-swapped: D[j][e] ----
    f32x4 acc[5][3];
#pragma unroll
    for (int a = 0; a < 5; ++a)
#pragma unroll
        for (int b = 0; b < 3; ++b) acc[a][b] = (f32x4){0.f, 0.f, 0.f, 0.f};

    __builtin_amdgcn_s_setprio(1);
#pragma unroll
    for (int kk = 0; kk < 5; ++kk) {
        const int ko = kk * 32 + g4 * 8;
        bf16x8 ah[3], al[3];
#pragma unroll
        for (int et = 0; et < 3; ++et) {
            ah[et] = *(const bf16x8*)&ein_hi[(et * 16 + r16) * KP_E + ko];
            al[et] = *(const bf16x8*)&ein_lo[(et * 16 + r16) * KP_E + ko];
        }
#pragma unroll
        for (int j5 = 0; j5 < 5; ++j5) {
            const size_t wo = (size_t)((jt0 + j5) * 16 + r16) * KP + ko;
            bf16x8 bh = *(const bf16x8*)&w1hi[wo];
            bf16x8 bl = *(const bf16x8*)&w1lo[wo];
#pragma unroll
            for (int et = 0; et < 3; ++et) {
                acc[j5][et] = __builtin_amdgcn_mfma_f32_16x16x32_bf16(bh, ah[et], acc[j5][et], 0, 0, 0);
                acc[j5][et] = __builtin_amdgcn_mfma_f32_16x16x32_bf16(bl, ah[et], acc[j5][et], 0, 0, 0);
                acc[j5][et] = __builtin_amdgcn_mfma_f32_16x16x32_bf16(bh, al[et], acc[j5][et], 0, 0, 0);
            }
        }
    }
    __builtin_amdgcn_s_setprio(0);

    // D[j][e]: j = (jt0+j5)*16 + g4*4 + r, e = et*16 + r16
    float4 b1v[5];
#pragma unroll
    for (int j5 = 0; j5 < 5; ++j5)
        b1v[j5] = *(const float4*)&b1p[(jt0 + j5) * 16 + g4 * 4];

    __syncthreads();   // all ein reads done before h overwrite

#pragma unroll
    for (int j5 = 0; j5 < 5; ++j5) {
#pragma unroll
        for (int et = 0; et < 3; ++et) {
            f32x4 a = acc[j5][et];
            float h0 = silu_f(a[0] + b1v[j5].x);
            float h1 = silu_f(a[1] + b1v[j5].y);
            float h2 = silu_f(a[2] + b1v[j5].z);
            float h3 = silu_f(a[3] + b1v[j5].w);
            uint2 uu;
            uu.x = packbf2(h0, h1);
            uu.y = packbf2(h2, h3);
            *(uint2*)&h_hi[(et * 16 + r16) * JP_H + (jt0 + j5) * 16 + g4 * 4] = uu;
        }
    }
    __syncthreads();

    // ---- MLP2: m[e][c]; waves 0..2; w2 frags from global ----
    if (w < 3) {
        f32x4 acc2 = (f32x4){0.f, 0.f, 0.f, 0.f};
        const unsigned short* hrow = &h_hi[(w * 16 + r16) * JP_H];
        const unsigned short* w2h = &w2tg[(size_t)r16 * JP_H];
        const unsigned short* w2l = &w2tg[(size_t)(16 + r16) * JP_H];
#pragma unroll
        for (int kk = 0; kk < 10; ++kk) {
            const int ko = kk * 32 + g4 * 8;
            bf16x8 hf = *(const bf16x8*)&hrow[ko];
            bf16x8 wh = *(const bf16x8*)&w2h[ko];
            bf16x8 wl = *(const bf16x8*)&w2l[ko];
            acc2 = __builtin_amdgcn_mfma_f32_16x16x32_bf16(hf, wh, acc2, 0, 0, 0);
            acc2 = __builtin_amdgcn_mfma_f32_16x16x32_bf16(hf, wl, acc2, 0, 0, 0);
        }
        float b2v = b2[r16];
#pragma unroll
        for (int r = 0; r < 4; ++r) {
            int e = w * 16 + g4 * 4 + r;
            float m = silu_f(acc2[r] + b2v);
            mij_bf[e * MSTR + r16] = bf16_rne(m);
            if (ge0 + e < E) atomicAdd(&m_i[(size_t)dstl[e] * 16 + r16], m);
        }
    }
    __syncthreads();

    // ---- coors MLP on MFMA ----
    if (w < 3) {
        bf16x8 afrag = *(const bf16x8*)&mij_bf[(w * 16 + r16) * MSTR + g4 * 8];
        f32x4 cacc[4];
#pragma unroll
        for (int jt = 0; jt < 4; ++jt) {
            bf16x8 bfrag = *(const bf16x8*)&cw1t[(jt * 16 + r16) * 32 + g4 * 8];
            cacc[jt] = __builtin_amdgcn_mfma_f32_16x16x32_bf16(afrag, bfrag,
                        (f32x4){0.f, 0.f, 0.f, 0.f}, 0, 0, 0);
        }
        float pw0 = 0.f, pw1 = 0.f, pw2 = 0.f, pw3 = 0.f;
#pragma unroll
        for (int jt = 0; jt < 4; ++jt) {
            float cb = cb1[jt * 16 + r16];
            float cw = cw2[jt * 16 + r16];
            pw0 += silu_f(cacc[jt][0] + cb) * cw;
            pw1 += silu_f(cacc[jt][1] + cb) * cw;
            pw2 += silu_f(cacc[jt][2] + cb) * cw;
            pw3 += silu_f(cacc[jt][3] + cb) * cw;
        }
#pragma unroll
        for (int s = 1; s < 16; s <<= 1) {
            pw0 += __shfl_xor(pw0, s, 16);
            pw1 += __shfl_xor(pw1, s, 16);
            pw2 += __shfl_xor(pw2, s, 16);
            pw3 += __shfl_xor(pw3, s, 16);
        }
        if (r16 == 0) {
            float cb2v = cb2[0];
            int e = w * 16 + g4 * 4;
            relc[e + 0][3] = pw0 + cb2v;
            relc[e + 1][3] = pw1 + cb2v;
            relc[e + 2][3] = pw2 + cb2v;
            relc[e + 3][3] = pw3 + cb2v;
        }
    }
    __syncthreads();

    // ---- scatter coors segment sums ----
    if (tid < EPB * 4) {
        int e = tid >> 2, c = tid & 3;
        if (ge0 + e < E) {
            int d = dstl[e];
            if (c < 3) atomicAdd(&cri[(size_t)d * 3 + c], relc[e][c]);
            else       atomicAdd(&cwi[d], relc[e][3]);
        }
    }
}

// ---------------- node kernel: 2 nodes per 256-thread block ----------------
// IN-PLACE SAFE (xin may alias xout). Re-zeroes accumulators for next layer.
__global__ __launch_bounds__(256) void node_kernel(
    const float* xin,
    float* __restrict__ m_i,
    float* __restrict__ cri,
    float* __restrict__ cwi,
    const float* __restrict__ nw1, const float* __restrict__ nb1,
    const float* __restrict__ nw2, const float* __restrict__ nb2,
    float* xout, int N)
{
    __shared__ __align__(16) float nin[2][80];
    __shared__ __align__(16) float hid[2][128];
    const int half = threadIdx.x >> 7, r = threadIdx.x & 127;
    const int n = blockIdx.x * 2 + half;
    const bool on = (n < N);

    if (on) {
        if (r < 64)      nin[half][r] = xin[(size_t)n * XDIM + r];
        else if (r < 80) nin[half][r] = m_i[(size_t)n * 16 + (r - 64)];
    }
    __syncthreads();
    if (on) {
        float p0 = 0.f, p1 = 0.f, p2 = 0.f, p3 = 0.f;
#pragma unroll
        for (int k = 0; k < 80; k += 16) {
            float4 a0 = *(const float4*)&nin[half][k];
            float4 a1 = *(const float4*)&nin[half][k + 4];
            float4 a2 = *(const float4*)&nin[half][k + 8];
            float4 a3 = *(const float4*)&nin[half][k + 12];
            p0 += a0.x * nw1[(k + 0) * 128 + r] + a0.y * nw1[(k + 1) * 128 + r]
                + a0.z * nw1[(k + 2) * 128 + r] + a0.w * nw1[(k + 3) * 128 + r];
            p1 += a1.x * nw1[(k + 4) * 128 + r] + a1.y * nw1[(k + 5) * 128 + r]
                + a1.z * nw1[(k + 6) * 128 + r] + a1.w * nw1[(k + 7) * 128 + r];
            p2 += a2.x * nw1[(k + 8) * 128 + r] + a2.y * nw1[(k + 9) * 128 + r]
                + a2.z * nw1[(k + 10) * 128 + r] + a2.w * nw1[(k + 11) * 128 + r];
            p3 += a3.x * nw1[(k + 12) * 128 + r] + a3.y * nw1[(k + 13) * 128 + r]
                + a3.z * nw1[(k + 14) * 128 + r] + a3.w * nw1[(k + 15) * 128 + r];
        }
        hid[half][r] = silu_f(nb1[r] + ((p0 + p1) + (p2 + p3)));
    }
    __syncthreads();
    if (on) {
        if (r < 64) {
            float p0 = 0.f, p1 = 0.f, p2 = 0.f, p3 = 0.f;
#pragma unroll
            for (int k = 0; k < 128; k += 16) {
                float4 a0 = *(const float4*)&hid[half][k];
                float4 a1 = *(const float4*)&hid[half][k + 4];
                float4 a2 = *(const float4*)&hid[half][k + 8];
                float4 a3 = *(const float4*)&hid[half][k + 12];
                p0 += a0.x * nw2[(k + 0) * 64 + r] + a0.y * nw2[(k + 1) * 64 + r]
                    + a0.z * nw2[(k + 2) * 64 + r] + a0.w * nw2[(k + 3) * 64 + r];
                p1 += a1.x * nw2[(k + 4) * 64 + r] + a1.y * nw2[(k + 5) * 64 + r]
                    + a1.z * nw2[(k + 6) * 64 + r] + a1.w * nw2[(k + 7) * 64 + r];
                p2 += a2.x * nw2[(k + 8) * 64 + r] + a2.y * nw2[(k + 9) * 64 + r]
                    + a2.z * nw2[(k + 10) * 64 + r] + a2.w * nw2[(k + 11) * 64 + r];
                p3 += a3.x * nw2[(k + 12) * 64 + r] + a3.y * nw2[(k + 13) * 64 + r]
                    + a3.z * nw2[(k + 14) * 64 + r] + a3.w * nw2[(k + 15) * 64 + r];
            }
            xout[(size_t)n * XDIM + r] = nb2[r] + ((p0 + p1) + (p2 + p3)) + nin[half][r];
        } else if (r < 67) {
            int c = r - 64;
            xout[(size_t)n * XDIM + r] =
                xin[(size_t)n * XDIM + r] + cwi[n] * cri[(size_t)n * 3 + c];
        }
    }
    __syncthreads();   // all acc reads done; re-zero for next layer's atomics
    if (on) {
        if (r < 16)      m_i[(size_t)n * 16 + r] = 0.f;
        else if (r < 19) cri[(size_t)n * 3 + (r - 16)] = 0.f;
        else if (r == 19) cwi[n] = 0.f;
    }
}

extern "C" void kernel_launch(void* const* d_in, const int* in_sizes, int n_in,
                              void* d_out, int out_size, void* d_ws, size_t ws_size,
                              hipStream_t stream) {
    const float* x     = (const float*)d_in[0];
    const int*   eidx  = (const int*)d_in[1];      // int32 (harness downcasts int64)
    const float* eattr = (const float*)d_in[2];
    const float* ew1   = (const float*)d_in[3];
    const float* eb1   = (const float*)d_in[4];
    const float* ew2   = (const float*)d_in[5];
    const float* eb2   = (const float*)d_in[6];
    const float* cw1   = (const float*)d_in[7];
    const float* cb1   = (const float*)d_in[8];
    const float* cw2   = (const float*)d_in[9];
    const float* cb2   = (const float*)d_in[10];
    const float* nw1   = (const float*)d_in[11];
    const float* nb1   = (const float*)d_in[12];
    const float* nw2   = (const float*)d_in[13];
    const float* nb2   = (const float*)d_in[14];

    const int N = in_sizes[0] / XDIM;
    const int E = in_sizes[1] / 2;

    // ws: acc(N*20 f32) | b1p(3*JP f32) | w1hi | w1lo (3*JP*KP u16) | w2tg | cw1t
    float* acc  = (float*)d_ws;
    float* m_i  = acc;
    float* cri  = acc + (size_t)N * 16;
    float* cwi  = acc + (size_t)N * 19;
    float* b1p  = acc + (size_t)N * 20;
    unsigned short* w1hi = (unsigned short*)(b1p + (size_t)3 * JP);
    unsigned short* w1lo = w1hi + (size_t)3 * JP * KP;
    unsigned short* w2tg = w1lo + (size_t)3 * JP * KP;
    unsigned short* cw1t = w2tg + (size_t)3 * 2 * 16 * JP_H;

    float* xwork = (float*)d_out;   // all layers in place on d_out

    copy_zero_kernel<<<2048, 256, 0, stream>>>(x, xwork, N * XDIM, acc, N * 20);
    prep_w1t<<<(3 * JP * KP + 255) / 256, 256, 0, stream>>>(ew1, w1hi, w1lo);
    prep_w2t<<<(3 * 16 * JP_H + 255) / 256, 256, 0, stream>>>(ew2, w2tg);
    prep_b1<<<(3 * JP + 255) / 256, 256, 0, stream>>>(eb1, b1p);
    prep_cw1t<<<(3 * 64 * 32 + 255) / 256, 256, 0, stream>>>(cw1, cw1t);

    for (int l = 0; l < 3; ++l) {
        edge_kernel<<<(E + EPB - 1) / EPB, 256, 0, stream>>>(
            xwork, eidx, eattr,
            w1hi + (size_t)l * JP * KP, w1lo + (size_t)l * JP * KP,
            b1p + (size_t)l * JP,
            w2tg + (size_t)l * 2 * 16 * JP_H,
            eb2 + (size_t)l * 16,
            cw1t + (size_t)l * 64 * 32,
            cb1 + (size_t)l * 64,
            cw2 + (size_t)l * 64, cb2 + l,
            m_i, cri, cwi, E, N);
        node_kernel<<<(N + 1) / 2, 256, 0, stream>>>(
            xwork, m_i, cri, cwi,
            nw1 + (size_t)l * 80 * 128, nb1 + (size_t)l * 128,
            nw2 + (size_t)l * 128 * 64, nb2 + (size_t)l * 64,
            xwork, N);
    }
}